// Round 4
// baseline (709.547 us; speedup 1.0000x reference)
//
#include <hip/hip_runtime.h>

typedef short short8 __attribute__((ext_vector_type(8)));
typedef float f32x4 __attribute__((ext_vector_type(4)));
typedef unsigned short u16;
typedef unsigned int u32;

__device__ __forceinline__ float b2f(u16 u){ union{u32 i; float f;} v; v.i=((u32)u)<<16; return v.f; }
__device__ __forceinline__ u16 f2b(float f){ union{float f; u32 i;} v; v.f=f; return (u16)((v.i + 0x7fffu + ((v.i>>16)&1u))>>16); }
__device__ __forceinline__ float loadv(const void* p, long i, bool isbf){
  return isbf ? b2f(((const u16*)p)[i]) : ((const float*)p)[i];
}

// ---------------- dtype detector: bf16 buffers vs fp32 buffers ----------------
__global__ void detect_bf16(const void* x, int n, int* flag){
  __shared__ int cnt;
  if (threadIdx.x==0) cnt = 0;
  __syncthreads();
  int m = n < 4096 ? n : 4096;
  int good = 0;
  for (int i = threadIdx.x; i < m; i += 256){
    u16 u = ((const u16*)x)[i];
    int e = (u >> 7) & 0xff;
    if (u == 0 || (e >= 100 && e <= 140)) good++;
  }
  atomicAdd(&cnt, good);
  __syncthreads();
  if (threadIdx.x==0){
    flag[0] = (cnt >= (m*3)/4) ? 1 : 0;
    flag[1] = 1;  // constant "is bf16" for internal buffers
  }
}

// ---------------- CSR build ----------------
__global__ void count_k(const int* __restrict__ dst, int* __restrict__ counts, int E){
  int e = blockIdx.x*256 + threadIdx.x;
  if (e < E) atomicAdd(&counts[dst[e]], 1);
}

__global__ __launch_bounds__(256) void scan_bsum(const int* __restrict__ counts, int* __restrict__ bsum, int N){
  __shared__ int sm[256];
  int t = threadIdx.x, i = blockIdx.x*256 + t;
  sm[t] = (i < N) ? counts[i] : 0;
  __syncthreads();
  for (int off = 128; off; off >>= 1){
    if (t < off) sm[t] += sm[t+off];
    __syncthreads();
  }
  if (t == 0) bsum[blockIdx.x] = sm[0];
}

__global__ __launch_bounds__(1024) void scan_top(const int* __restrict__ bsum, int* __restrict__ bscan, int B){
  __shared__ int sm[1024];
  int t = threadIdx.x;
  int v = (t < B) ? bsum[t] : 0;
  sm[t] = v;
  __syncthreads();
  for (int off = 1; off < 1024; off <<= 1){
    int x = (t >= off) ? sm[t-off] : 0;
    __syncthreads();
    sm[t] += x;
    __syncthreads();
  }
  if (t < B) bscan[t] = sm[t] - v;   // exclusive
}

__global__ __launch_bounds__(256) void scan_final(const int* __restrict__ counts, const int* __restrict__ bscan,
                                                  int* __restrict__ rp, int N, int E){
  __shared__ int sm[256];
  int t = threadIdx.x, i = blockIdx.x*256 + t;
  int v = (i < N) ? counts[i] : 0;
  sm[t] = v;
  __syncthreads();
  for (int off = 1; off < 256; off <<= 1){
    int x = (t >= off) ? sm[t-off] : 0;
    __syncthreads();
    sm[t] += x;
    __syncthreads();
  }
  if (i < N) rp[i] = bscan[blockIdx.x] + sm[t] - v;
  if (i == 0) rp[N] = E;
}

__global__ void scatter_k(const int* __restrict__ src, const int* __restrict__ dst,
                          const int* __restrict__ rp, int* __restrict__ cur,
                          int* __restrict__ psrc, int* __restrict__ pdst, int E){
  int e = blockIdx.x*256 + threadIdx.x;
  if (e < E){
    int d = dst[e];
    int pos = rp[d] + atomicAdd(&cur[d], 1);
    psrc[pos] = src[e];
    pdst[pos] = d;
  }
}

// ---------------- GEMM: OUT[N,M] = X[N,128] * W[128,M], bf16 out, fp32 acc ----------------
template<int M>
__global__ __launch_bounds__(256) void gemm_k(const void* __restrict__ X, const void* __restrict__ W,
                                              u16* __restrict__ OUT, int N,
                                              const int* __restrict__ flagX, const int* __restrict__ flagW){
  __shared__ u16 wt[M][136];            // W^T, +8 pad: 2-way bank alias only (free)
  const bool xbf = *flagX != 0;
  const bool wbf = *flagW != 0;
  int tid = threadIdx.x;
  for (int i = tid; i < 128*M; i += 256){
    int k = i / M, c = i % M;
    wt[c][k] = wbf ? ((const u16*)W)[i] : f2b(((const float*)W)[i]);
  }
  __syncthreads();
  int wave = tid >> 6, lane = tid & 63;
  int quad = lane >> 4, l16 = lane & 15;
  int rowbase = blockIdx.x*64 + wave*16;
  int rr = rowbase + l16; if (rr >= N) rr = N-1;
  const int NT = M/16;
  f32x4 acc[NT];
  #pragma unroll
  for (int t=0;t<NT;t++) acc[t] = (f32x4){0.f,0.f,0.f,0.f};
  #pragma unroll
  for (int kt = 0; kt < 4; kt++){
    int kb = kt*32 + quad*8;
    short8 a;
    if (xbf){
      a = *(const short8*)((const u16*)X + (size_t)rr*128 + kb);
    } else {
      const float* xf = (const float*)X + (size_t)rr*128 + kb;
      #pragma unroll
      for (int j=0;j<8;j++) a[j] = (short)f2b(xf[j]);
    }
    #pragma unroll
    for (int t=0;t<NT;t++){
      short8 b = *(const short8*)&wt[t*16 + l16][kb];
      acc[t] = __builtin_amdgcn_mfma_f32_16x16x32_bf16(a, b, acc[t], 0, 0, 0);
    }
  }
  #pragma unroll
  for (int t=0;t<NT;t++){
    #pragma unroll
    for (int r=0;r<4;r++){
      int row = rowbase + quad*4 + r;
      if (row < N) OUT[(size_t)row*M + t*16 + l16] = f2b(acc[t][r]);
    }
  }
}

// ---------------- attention pre-logits: al[n,h] = sum_c h[n,h,c]*a[h,c] ----------------
template<int C>
__global__ __launch_bounds__(256) void al_k(const u16* __restrict__ Hm, const void* __restrict__ as_,
                     const void* __restrict__ ad_,
                     float* __restrict__ als, float* __restrict__ ald, int N, const int* __restrict__ flag){
  __shared__ float s_as[4*C], s_ad[4*C];
  const bool isbf = *flag != 0;
  for (int i = threadIdx.x; i < 4*C; i += 256){
    s_as[i] = loadv(as_, i, isbf);
    s_ad[i] = loadv(ad_, i, isbf);
  }
  __syncthreads();
  int idx = blockIdx.x*256 + threadIdx.x;
  if (idx >= N*4) return;
  int n = idx >> 2, h = idx & 3;
  const short8* row = (const short8*)(Hm + (size_t)n*(4*C) + h*C);
  float ss = 0.f, sd = 0.f;
  #pragma unroll
  for (int v = 0; v < C/8; v++){
    short8 pk = row[v];
    #pragma unroll
    for (int j = 0; j < 8; j++){
      union{u32 i; float f;} u; u.i = ((u32)(u16)pk[j]) << 16;
      ss += u.f * s_as[h*C + v*8 + j];
      sd += u.f * s_ad[h*C + v*8 + j];
    }
  }
  als[idx] = ss;
  ald[idx] = sd;
}

// ---------------- edge-parallel exp(leaky(logit)) in CSR order ----------------
__global__ __launch_bounds__(256) void edge_ex(const int* __restrict__ psrc, const int* __restrict__ pdst,
    const float* __restrict__ als, const float* __restrict__ ald,
    float* __restrict__ pex, int E4){
  int t = blockIdx.x*256 + threadIdx.x;
  if (t >= E4) return;
  int p = t >> 2, h = t & 3;
  float lg = als[psrc[p]*4 + h] + ald[pdst[p]*4 + h];
  lg = lg > 0.f ? lg : 0.2f*lg;
  pex[t] = __expf(lg);
}

// ---------------- per-(node,head) softmax denominator -> reciprocal ----------------
__global__ __launch_bounds__(256) void inv_k(const float* __restrict__ pex, const int* __restrict__ rp,
    float* __restrict__ invs, int N4){
  int t = blockIdx.x*256 + threadIdx.x;
  if (t >= N4) return;
  int n = t >> 2, h = t & 3;
  int beg = rp[n], end = rp[n+1];
  float s = 0.f;
  for (int p = beg; p < end; p++) s += pex[4*p + h];
  invs[t] = 1.f/(s + 1e-16f);
}

// ---------------- layer-1 aggregation: wave per node, slim gather loop ----------------
// ex/inv precomputed; inner loop = row gather + fma only, 2-edge software pipeline.
__global__ __launch_bounds__(256) void agg1(const u16* __restrict__ h1,
    const float* __restrict__ pex, const float* __restrict__ invs, const void* __restrict__ b1,
    const int* __restrict__ rp, const int* __restrict__ psrc,
    u16* __restrict__ hrelu, int N, const int* __restrict__ flag){
  const bool isbf = *flag != 0;
  int wave = threadIdx.x >> 6, lane = threadIdx.x & 63;
  int node = blockIdx.x*4 + wave;
  bool live = node < N;
  int nd = live ? node : 0;
  int hd = lane >> 4;
  int beg = __builtin_amdgcn_readfirstlane(rp[nd]);
  int end = __builtin_amdgcn_readfirstlane(rp[nd+1]);
  if (!live){ beg = 0; end = 0; }
  float inv = invs[nd*4 + hd];
  const u16* hb = h1 + (lane << 1);
  float a0 = 0.f, a1 = 0.f;
  int j = beg;
  int s0 = 0, s1 = 0; float e0 = 0.f, e1 = 0.f;
  if (j < end){ s0 = psrc[j]; e0 = pex[4*j + hd]; }
  if (j+1 < end){ s1 = psrc[j+1]; e1 = pex[4*j + 4 + hd]; }
  while (j < end){
    int jn = j + 2;
    int t0 = 0, t1 = 0; float f0 = 0.f, f1 = 0.f;
    if (jn < end){ t0 = psrc[jn]; f0 = pex[4*jn + hd]; }
    if (jn+1 < end){ t1 = psrc[jn+1]; f1 = pex[4*jn + 4 + hd]; }
    u32 p0 = *(const u32*)(hb + ((size_t)s0 << 7));
    u32 p1 = *(const u32*)(hb + ((size_t)s1 << 7));
    union{u32 i; float f;} w;
    w.i = p0 << 16;         a0 += e0 * w.f;
    w.i = p0 & 0xffff0000u; a1 += e0 * w.f;
    w.i = p1 << 16;         a0 += e1 * w.f;
    w.i = p1 & 0xffff0000u; a1 += e1 * w.f;
    s0 = t0; s1 = t1; e0 = f0; e1 = f1;
    j = jn;
  }
  if (live){
    float v0 = a0*inv + loadv(b1, 2*lane,     isbf);
    float v1 = a1*inv + loadv(b1, 2*lane + 1, isbf);
    v0 = v0 > 0.f ? v0 : 0.f;
    v1 = v1 > 0.f ? v1 : 0.f;
    u32 packed = (u32)f2b(v0) | ((u32)f2b(v1) << 16);
    *(u32*)(hrelu + (size_t)node*128 + 2*lane) = packed;
  }
}

// ---------------- layer-2 aggregation + head-mean + bias + log_softmax ----------------
__global__ __launch_bounds__(256) void agg2(const u16* __restrict__ h2,
    const float* __restrict__ pex, const float* __restrict__ invs, const void* __restrict__ b2,
    const int* __restrict__ rp, const int* __restrict__ psrc,
    void* __restrict__ out, int N, const int* __restrict__ flag){
  __shared__ float sm[4][160];
  const bool isbf = *flag != 0;
  int wave = threadIdx.x >> 6, lane = threadIdx.x & 63;
  int node = blockIdx.x*4 + wave;
  bool live = node < N;
  int nd = live ? node : 0;
  int hA = lane / 20;                 // pairA: lane -> channels 2l,2l+1 ; head = pair/20
  bool hasB = lane < 16;              // pairB: 64+lane -> channels 128+2l (head 3)
  int beg = __builtin_amdgcn_readfirstlane(rp[nd]);
  int end = __builtin_amdgcn_readfirstlane(rp[nd+1]);
  if (!live){ beg = 0; end = 0; }
  float invA = invs[nd*4 + hA];
  float invB = invs[nd*4 + 3];
  float aA0 = 0.f, aA1 = 0.f, aB0 = 0.f, aB1 = 0.f;
  int j = beg;
  int s0 = 0, s1 = 0; float eA0 = 0.f, eA1 = 0.f, eB0 = 0.f, eB1 = 0.f;
  if (j < end){ s0 = psrc[j]; eA0 = pex[4*j + hA]; eB0 = pex[4*j + 3]; }
  if (j+1 < end){ s1 = psrc[j+1]; eA1 = pex[4*j + 4 + hA]; eB1 = pex[4*j + 7]; }
  while (j < end){
    int jn = j + 2;
    int t0 = 0, t1 = 0; float fA0 = 0.f, fA1 = 0.f, fB0 = 0.f, fB1 = 0.f;
    if (jn < end){ t0 = psrc[jn]; fA0 = pex[4*jn + hA]; fB0 = pex[4*jn + 3]; }
    if (jn+1 < end){ t1 = psrc[jn+1]; fA1 = pex[4*jn + 4 + hA]; fB1 = pex[4*jn + 7]; }
    const u16* r0 = h2 + (size_t)s0*160 + (lane << 1);
    const u16* r1 = h2 + (size_t)s1*160 + (lane << 1);
    u32 p0 = *(const u32*)r0;
    u32 p1 = *(const u32*)r1;
    u32 q0 = 0, q1 = 0;
    if (hasB){
      q0 = *(const u32*)(r0 + 128);
      q1 = *(const u32*)(r1 + 128);
    }
    union{u32 i; float f;} w;
    w.i = p0 << 16;         aA0 += eA0 * w.f;
    w.i = p0 & 0xffff0000u; aA1 += eA0 * w.f;
    w.i = p1 << 16;         aA0 += eA1 * w.f;
    w.i = p1 & 0xffff0000u; aA1 += eA1 * w.f;
    if (hasB){
      w.i = q0 << 16;         aB0 += eB0 * w.f;
      w.i = q0 & 0xffff0000u; aB1 += eB0 * w.f;
      w.i = q1 << 16;         aB0 += eB1 * w.f;
      w.i = q1 & 0xffff0000u; aB1 += eB1 * w.f;
    }
    s0 = t0; s1 = t1; eA0 = fA0; eA1 = fA1; eB0 = fB0; eB1 = fB1;
    j = jn;
  }
  sm[wave][2*lane]     = aA0*invA;
  sm[wave][2*lane + 1] = aA1*invA;
  if (hasB){
    sm[wave][128 + 2*lane] = aB0*invB;
    sm[wave][129 + 2*lane] = aB1*invB;
  }
  __syncthreads();
  float v = -__builtin_inff();
  if (lane < 40)
    v = (sm[wave][lane] + sm[wave][40+lane] + sm[wave][80+lane] + sm[wave][120+lane]) * 0.25f
        + loadv(b2, lane, isbf);
  float mxo = v;
  for (int o = 32; o; o >>= 1) mxo = fmaxf(mxo, __shfl_xor(mxo, o));
  float ex = (lane < 40) ? __expf(v - mxo) : 0.f;
  float S = ex;
  for (int o = 32; o; o >>= 1) S += __shfl_xor(S, o);
  if (live && lane < 40){
    float r = v - mxo - __logf(S);
    if (isbf) ((u16*)out)[(size_t)node*40 + lane] = f2b(r);
    else      ((float*)out)[(size_t)node*40 + lane] = r;
  }
}

extern "C" void kernel_launch(void* const* d_in, const int* in_sizes, int n_in,
                              void* d_out, int out_size, void* d_ws, size_t ws_size,
                              hipStream_t stream){
  const void* x   = d_in[0];
  const int*  ei  = (const int*)d_in[1];
  const void* W1  = d_in[2];
  const void* as1 = d_in[3];
  const void* ad1 = d_in[4];
  const void* b1  = d_in[5];
  const void* W2  = d_in[6];
  const void* as2 = d_in[7];
  const void* ad2 = d_in[8];
  const void* b2  = d_in[9];

  const int N = in_sizes[0] / 128;
  const int E = in_sizes[1] / 2;
  const int* esrc = ei;
  const int* edst = ei + E;

  char* w = (char*)d_ws;
  size_t off = 0;
  auto take = [&](size_t bytes)->void*{
    void* p = w + off;
    off = (off + bytes + 255) & ~(size_t)255;
    return p;
  };
  u16*   h12    = (u16*)take((size_t)N*160*2);   // h1 [N,128] then h2 [N,160] (aliased)
  u16*   hrelu  = (u16*)take((size_t)N*128*2);
  float* als1   = (float*)take((size_t)N*4*4);
  float* ald1   = (float*)take((size_t)N*4*4);
  float* als2   = (float*)take((size_t)N*4*4);
  float* ald2   = (float*)take((size_t)N*4*4);
  int*   rowptr = (int*)take((size_t)(N+1)*4);
  int*   counts = (int*)take((size_t)N*4);
  int*   bsum   = (int*)take(1024*4);
  int*   bscan  = (int*)take(1024*4);
  int*   psrc   = (int*)take((size_t)E*4);
  int*   pdst   = (int*)take((size_t)E*4);
  float* pex    = (float*)take((size_t)E*4*4);
  float* invs   = (float*)take((size_t)N*4*4);
  int*   flag   = (int*)take(64);

  const int B = (N + 255) / 256;

  detect_bf16<<<1, 256, 0, stream>>>(x, N*128, flag);

  // CSR by dst
  hipMemsetAsync(counts, 0, (size_t)N*4, stream);
  count_k<<<(E+255)/256, 256, 0, stream>>>(edst, counts, E);
  scan_bsum<<<B, 256, 0, stream>>>(counts, bsum, N);
  scan_top<<<1, 1024, 0, stream>>>(bsum, bscan, B);
  scan_final<<<B, 256, 0, stream>>>(counts, bscan, rowptr, N, E);
  hipMemsetAsync(counts, 0, (size_t)N*4, stream);
  scatter_k<<<(E+255)/256, 256, 0, stream>>>(esrc, edst, rowptr, counts, psrc, pdst, E);

  // layer 1
  gemm_k<128><<<(N+63)/64, 256, 0, stream>>>(x, W1, h12, N, flag, flag);
  al_k<32><<<(4*N+255)/256, 256, 0, stream>>>(h12, as1, ad1, als1, ald1, N, flag);
  edge_ex<<<(4*E+255)/256, 256, 0, stream>>>(psrc, pdst, als1, ald1, pex, 4*E);
  inv_k<<<(4*N+255)/256, 256, 0, stream>>>(pex, rowptr, invs, 4*N);
  agg1<<<(N+3)/4, 256, 0, stream>>>(h12, pex, invs, b1, rowptr, psrc, hrelu, N, flag);

  // layer 2 (h2 overwrites h1 region; hrelu input is internal bf16 -> flag+1)
  gemm_k<160><<<(N+63)/64, 256, 0, stream>>>(hrelu, W2, h12, N, flag+1, flag);
  al_k<40><<<(4*N+255)/256, 256, 0, stream>>>(h12, as2, ad2, als2, ald2, N, flag);
  edge_ex<<<(4*E+255)/256, 256, 0, stream>>>(psrc, pdst, als2, ald2, pex, 4*E);
  inv_k<<<(4*N+255)/256, 256, 0, stream>>>(pex, rowptr, invs, 4*N);
  agg2<<<(N+3)/4, 256, 0, stream>>>(h12, pex, invs, b2, rowptr, psrc, d_out, N, flag);
}

// Round 5
// 695.184 us; speedup vs baseline: 1.0207x; 1.0207x over previous
//
#include <hip/hip_runtime.h>

typedef short short8 __attribute__((ext_vector_type(8)));
typedef float f32x4 __attribute__((ext_vector_type(4)));
typedef unsigned short u16;
typedef unsigned int u32;

__device__ __forceinline__ float b2f(u16 u){ union{u32 i; float f;} v; v.i=((u32)u)<<16; return v.f; }
__device__ __forceinline__ u16 f2b(float f){ union{float f; u32 i;} v; v.f=f; return (u16)((v.i + 0x7fffu + ((v.i>>16)&1u))>>16); }
__device__ __forceinline__ float loadv(const void* p, long i, bool isbf){
  return isbf ? b2f(((const u16*)p)[i]) : ((const float*)p)[i];
}

// ---------------- dtype detector: bf16 buffers vs fp32 buffers ----------------
__global__ void detect_bf16(const void* x, int n, int* flag){
  __shared__ int cnt;
  if (threadIdx.x==0) cnt = 0;
  __syncthreads();
  int m = n < 4096 ? n : 4096;
  int good = 0;
  for (int i = threadIdx.x; i < m; i += 256){
    u16 u = ((const u16*)x)[i];
    int e = (u >> 7) & 0xff;
    if (u == 0 || (e >= 100 && e <= 140)) good++;
  }
  atomicAdd(&cnt, good);
  __syncthreads();
  if (threadIdx.x==0){
    flag[0] = (cnt >= (m*3)/4) ? 1 : 0;
    flag[1] = 1;  // constant "is bf16" for internal buffers
  }
}

// ---------------- CSR build ----------------
__global__ void count_k(const int* __restrict__ dst, int* __restrict__ counts, int E){
  int e = blockIdx.x*256 + threadIdx.x;
  if (e < E) atomicAdd(&counts[dst[e]], 1);
}

__global__ __launch_bounds__(256) void scan_bsum(const int* __restrict__ counts, int* __restrict__ bsum, int N){
  __shared__ int sm[256];
  int t = threadIdx.x, i = blockIdx.x*256 + t;
  sm[t] = (i < N) ? counts[i] : 0;
  __syncthreads();
  for (int off = 128; off; off >>= 1){
    if (t < off) sm[t] += sm[t+off];
    __syncthreads();
  }
  if (t == 0) bsum[blockIdx.x] = sm[0];
}

__global__ __launch_bounds__(1024) void scan_top(const int* __restrict__ bsum, int* __restrict__ bscan, int B){
  __shared__ int sm[1024];
  int t = threadIdx.x;
  int v = (t < B) ? bsum[t] : 0;
  sm[t] = v;
  __syncthreads();
  for (int off = 1; off < 1024; off <<= 1){
    int x = (t >= off) ? sm[t-off] : 0;
    __syncthreads();
    sm[t] += x;
    __syncthreads();
  }
  if (t < B) bscan[t] = sm[t] - v;   // exclusive
}

__global__ __launch_bounds__(256) void scan_final(const int* __restrict__ counts, const int* __restrict__ bscan,
                                                  int* __restrict__ rp, int N, int E){
  __shared__ int sm[256];
  int t = threadIdx.x, i = blockIdx.x*256 + t;
  int v = (i < N) ? counts[i] : 0;
  sm[t] = v;
  __syncthreads();
  for (int off = 1; off < 256; off <<= 1){
    int x = (t >= off) ? sm[t-off] : 0;
    __syncthreads();
    sm[t] += x;
    __syncthreads();
  }
  if (i < N) rp[i] = bscan[blockIdx.x] + sm[t] - v;
  if (i == 0) rp[N] = E;
}

__global__ void scatter_k(const int* __restrict__ src, const int* __restrict__ dst,
                          const int* __restrict__ rp, int* __restrict__ cur,
                          int* __restrict__ psrc, int E){
  int e = blockIdx.x*256 + threadIdx.x;
  if (e < E){
    int d = dst[e];
    int pos = rp[d] + atomicAdd(&cur[d], 1);
    psrc[pos] = src[e];
  }
}

// ---------------- GEMM: OUT[N,M] = X[N,128] * W[128,M], bf16 out, fp32 acc ----------------
template<int M>
__global__ __launch_bounds__(256) void gemm_k(const void* __restrict__ X, const void* __restrict__ W,
                                              u16* __restrict__ OUT, int N,
                                              const int* __restrict__ flagX, const int* __restrict__ flagW){
  __shared__ u16 wt[M][136];            // W^T, +8 pad: 2-way bank alias only (free)
  const bool xbf = *flagX != 0;
  const bool wbf = *flagW != 0;
  int tid = threadIdx.x;
  for (int i = tid; i < 128*M; i += 256){
    int k = i / M, c = i % M;
    wt[c][k] = wbf ? ((const u16*)W)[i] : f2b(((const float*)W)[i]);
  }
  __syncthreads();
  int wave = tid >> 6, lane = tid & 63;
  int quad = lane >> 4, l16 = lane & 15;
  int rowbase = blockIdx.x*64 + wave*16;
  int rr = rowbase + l16; if (rr >= N) rr = N-1;
  const int NT = M/16;
  f32x4 acc[NT];
  #pragma unroll
  for (int t=0;t<NT;t++) acc[t] = (f32x4){0.f,0.f,0.f,0.f};
  #pragma unroll
  for (int kt = 0; kt < 4; kt++){
    int kb = kt*32 + quad*8;
    short8 a;
    if (xbf){
      a = *(const short8*)((const u16*)X + (size_t)rr*128 + kb);
    } else {
      const float* xf = (const float*)X + (size_t)rr*128 + kb;
      #pragma unroll
      for (int j=0;j<8;j++) a[j] = (short)f2b(xf[j]);
    }
    #pragma unroll
    for (int t=0;t<NT;t++){
      short8 b = *(const short8*)&wt[t*16 + l16][kb];
      acc[t] = __builtin_amdgcn_mfma_f32_16x16x32_bf16(a, b, acc[t], 0, 0, 0);
    }
  }
  #pragma unroll
  for (int t=0;t<NT;t++){
    #pragma unroll
    for (int r=0;r<4;r++){
      int row = rowbase + quad*4 + r;
      if (row < N) OUT[(size_t)row*M + t*16 + l16] = f2b(acc[t][r]);
    }
  }
}

// ---------------- attention pre-logits: al[n,h] = sum_c h[n,h,c]*a[h,c] ----------------
template<int C>
__global__ __launch_bounds__(256) void al_k(const u16* __restrict__ Hm, const void* __restrict__ as_,
                     const void* __restrict__ ad_,
                     float* __restrict__ als, float* __restrict__ ald, int N, const int* __restrict__ flag){
  __shared__ float s_as[4*C], s_ad[4*C];
  const bool isbf = *flag != 0;
  for (int i = threadIdx.x; i < 4*C; i += 256){
    s_as[i] = loadv(as_, i, isbf);
    s_ad[i] = loadv(ad_, i, isbf);
  }
  __syncthreads();
  int idx = blockIdx.x*256 + threadIdx.x;
  if (idx >= N*4) return;
  int n = idx >> 2, h = idx & 3;
  const short8* row = (const short8*)(Hm + (size_t)n*(4*C) + h*C);
  float ss = 0.f, sd = 0.f;
  #pragma unroll
  for (int v = 0; v < C/8; v++){
    short8 pk = row[v];
    #pragma unroll
    for (int j = 0; j < 8; j++){
      union{u32 i; float f;} u; u.i = ((u32)(u16)pk[j]) << 16;
      ss += u.f * s_as[h*C + v*8 + j];
      sd += u.f * s_ad[h*C + v*8 + j];
    }
  }
  als[idx] = ss;
  ald[idx] = sd;
}

// ---------------- layer-1 aggregation: wave per node, 4-deep pipelined gather ----------------
// ex computed inline (dst==node so ald is a group constant); softmax denominator
// accumulated inline per 16-lane group (identical in all lanes, no reduction needed).
__global__ __launch_bounds__(256) void agg1(const u16* __restrict__ h1,
    const float* __restrict__ als, const float* __restrict__ ald, const void* __restrict__ b1,
    const int* __restrict__ rp, const int* __restrict__ psrc,
    u16* __restrict__ hrelu, int N, const int* __restrict__ flag){
  const bool isbf = *flag != 0;
  int wave = threadIdx.x >> 6, lane = threadIdx.x & 63;
  int node = blockIdx.x*4 + wave;
  bool live = node < N;
  int nd = live ? node : 0;
  int hd = lane >> 4;
  int beg = __builtin_amdgcn_readfirstlane(rp[nd]);
  int end = __builtin_amdgcn_readfirstlane(rp[nd+1]);
  if (!live){ beg = 0; end = 0; }
  float aldv = ald[nd*4 + hd];
  const u16* hb = h1 + (lane << 1);
  float a0 = 0.f, a1 = 0.f, sum = 0.f;
  float cav[4]; u32 cp[4]; bool cv[4];
  #pragma unroll
  for (int i=0;i<4;i++){
    int e = beg + i; bool v = e < end;
    int idx = v ? e : (end > beg ? end-1 : 0);
    int s = psrc[idx];
    cv[i] = v;
    cav[i] = als[s*4 + hd];
    cp[i]  = *(const u32*)(hb + ((size_t)s << 7));
  }
  for (int j = beg; j < end; j += 4){
    int jn = j + 4;
    float nav[4]; u32 np[4]; bool nv[4];
    #pragma unroll
    for (int i=0;i<4;i++){
      int e = jn + i; bool v = e < end;
      int idx = v ? e : end-1;
      int s = psrc[idx];
      nv[i] = v;
      nav[i] = als[s*4 + hd];
      np[i]  = *(const u32*)(hb + ((size_t)s << 7));
    }
    #pragma unroll
    for (int i=0;i<4;i++){
      float lg = cav[i] + aldv;
      lg = lg > 0.f ? lg : 0.2f*lg;
      float ex = cv[i] ? __expf(lg) : 0.f;
      sum += ex;
      union{u32 i; float f;} w;
      w.i = cp[i] << 16;         a0 += ex * w.f;
      w.i = cp[i] & 0xffff0000u; a1 += ex * w.f;
    }
    #pragma unroll
    for (int i=0;i<4;i++){ cav[i]=nav[i]; cp[i]=np[i]; cv[i]=nv[i]; }
  }
  if (live){
    float inv = 1.f/(sum + 1e-16f);
    float v0 = a0*inv + loadv(b1, 2*lane,     isbf);
    float v1 = a1*inv + loadv(b1, 2*lane + 1, isbf);
    v0 = v0 > 0.f ? v0 : 0.f;
    v1 = v1 > 0.f ? v1 : 0.f;
    u32 packed = (u32)f2b(v0) | ((u32)f2b(v1) << 16);
    *(u32*)(hrelu + (size_t)node*128 + 2*lane) = packed;
  }
}

// ---------------- layer-2 aggregation + head-mean + bias + log_softmax ----------------
__global__ __launch_bounds__(256) void agg2(const u16* __restrict__ h2,
    const float* __restrict__ als, const float* __restrict__ ald, const void* __restrict__ b2,
    const int* __restrict__ rp, const int* __restrict__ psrc,
    void* __restrict__ out, int N, const int* __restrict__ flag){
  __shared__ float sm[4][160];
  const bool isbf = *flag != 0;
  int wave = threadIdx.x >> 6, lane = threadIdx.x & 63;
  int node = blockIdx.x*4 + wave;
  bool live = node < N;
  int nd = live ? node : 0;
  int hA = lane / 20;                 // pairA: lane -> channels 2l,2l+1 ; head = pair/20
  bool hasB = lane < 16;              // pairB: 64+lane -> channels 128+2l (head 3)
  int beg = __builtin_amdgcn_readfirstlane(rp[nd]);
  int end = __builtin_amdgcn_readfirstlane(rp[nd+1]);
  if (!live){ beg = 0; end = 0; }
  float aldA = ald[nd*4 + hA];
  float aldB = ald[nd*4 + 3];
  const u16* hb = h2 + (lane << 1);
  float aA0 = 0.f, aA1 = 0.f, aB0 = 0.f, aB1 = 0.f, sumA = 0.f, sumB = 0.f;
  float cavA[4], cavB[4]; u32 cp[4], cq[4]; bool cv[4];
  #pragma unroll
  for (int i=0;i<4;i++){
    int e = beg + i; bool v = e < end;
    int idx = v ? e : (end > beg ? end-1 : 0);
    int s = psrc[idx];
    cv[i] = v;
    cavA[i] = als[s*4 + hA];
    cp[i]   = *(const u32*)(hb + (size_t)s*160);
    if (hasB){
      cavB[i] = als[s*4 + 3];
      cq[i]   = *(const u32*)(hb + (size_t)s*160 + 128);
    }
  }
  for (int j = beg; j < end; j += 4){
    int jn = j + 4;
    float navA[4], navB[4]; u32 np[4], nq[4]; bool nv[4];
    #pragma unroll
    for (int i=0;i<4;i++){
      int e = jn + i; bool v = e < end;
      int idx = v ? e : end-1;
      int s = psrc[idx];
      nv[i] = v;
      navA[i] = als[s*4 + hA];
      np[i]   = *(const u32*)(hb + (size_t)s*160);
      if (hasB){
        navB[i] = als[s*4 + 3];
        nq[i]   = *(const u32*)(hb + (size_t)s*160 + 128);
      }
    }
    #pragma unroll
    for (int i=0;i<4;i++){
      float lgA = cavA[i] + aldA;
      lgA = lgA > 0.f ? lgA : 0.2f*lgA;
      float exA = cv[i] ? __expf(lgA) : 0.f;
      sumA += exA;
      union{u32 i; float f;} w;
      w.i = cp[i] << 16;         aA0 += exA * w.f;
      w.i = cp[i] & 0xffff0000u; aA1 += exA * w.f;
      if (hasB){
        float lgB = cavB[i] + aldB;
        lgB = lgB > 0.f ? lgB : 0.2f*lgB;
        float exB = cv[i] ? __expf(lgB) : 0.f;
        sumB += exB;
        w.i = cq[i] << 16;         aB0 += exB * w.f;
        w.i = cq[i] & 0xffff0000u; aB1 += exB * w.f;
      }
    }
    #pragma unroll
    for (int i=0;i<4;i++){
      cavA[i]=navA[i]; cp[i]=np[i]; cv[i]=nv[i];
      if (hasB){ cavB[i]=navB[i]; cq[i]=nq[i]; }
    }
  }
  float invA = 1.f/(sumA + 1e-16f);
  sm[wave][2*lane]     = aA0*invA;
  sm[wave][2*lane + 1] = aA1*invA;
  if (hasB){
    float invB = 1.f/(sumB + 1e-16f);
    sm[wave][128 + 2*lane] = aB0*invB;
    sm[wave][129 + 2*lane] = aB1*invB;
  }
  __syncthreads();
  float v = -__builtin_inff();
  if (lane < 40)
    v = (sm[wave][lane] + sm[wave][40+lane] + sm[wave][80+lane] + sm[wave][120+lane]) * 0.25f
        + loadv(b2, lane, isbf);
  float mxo = v;
  for (int o = 32; o; o >>= 1) mxo = fmaxf(mxo, __shfl_xor(mxo, o));
  float ex = (lane < 40) ? __expf(v - mxo) : 0.f;
  float S = ex;
  for (int o = 32; o; o >>= 1) S += __shfl_xor(S, o);
  if (live && lane < 40){
    float r = v - mxo - __logf(S);
    if (isbf) ((u16*)out)[(size_t)node*40 + lane] = f2b(r);
    else      ((float*)out)[(size_t)node*40 + lane] = r;
  }
}

extern "C" void kernel_launch(void* const* d_in, const int* in_sizes, int n_in,
                              void* d_out, int out_size, void* d_ws, size_t ws_size,
                              hipStream_t stream){
  const void* x   = d_in[0];
  const int*  ei  = (const int*)d_in[1];
  const void* W1  = d_in[2];
  const void* as1 = d_in[3];
  const void* ad1 = d_in[4];
  const void* b1  = d_in[5];
  const void* W2  = d_in[6];
  const void* as2 = d_in[7];
  const void* ad2 = d_in[8];
  const void* b2  = d_in[9];

  const int N = in_sizes[0] / 128;
  const int E = in_sizes[1] / 2;
  const int* esrc = ei;
  const int* edst = ei + E;

  char* w = (char*)d_ws;
  size_t off = 0;
  auto take = [&](size_t bytes)->void*{
    void* p = w + off;
    off = (off + bytes + 255) & ~(size_t)255;
    return p;
  };
  u16*   h12    = (u16*)take((size_t)N*160*2);   // h1 [N,128] then h2 [N,160] (aliased)
  u16*   hrelu  = (u16*)take((size_t)N*128*2);
  float* als1   = (float*)take((size_t)N*4*4);
  float* ald1   = (float*)take((size_t)N*4*4);
  float* als2   = (float*)take((size_t)N*4*4);
  float* ald2   = (float*)take((size_t)N*4*4);
  int*   rowptr = (int*)take((size_t)(N+1)*4);
  int*   counts = (int*)take((size_t)N*4);
  int*   bsum   = (int*)take(1024*4);
  int*   bscan  = (int*)take(1024*4);
  int*   psrc   = (int*)take((size_t)E*4);
  int*   flag   = (int*)take(64);

  const int B = (N + 255) / 256;

  detect_bf16<<<1, 256, 0, stream>>>(x, N*128, flag);

  // CSR by dst
  hipMemsetAsync(counts, 0, (size_t)N*4, stream);
  count_k<<<(E+255)/256, 256, 0, stream>>>(edst, counts, E);
  scan_bsum<<<B, 256, 0, stream>>>(counts, bsum, N);
  scan_top<<<1, 1024, 0, stream>>>(bsum, bscan, B);
  scan_final<<<B, 256, 0, stream>>>(counts, bscan, rowptr, N, E);
  hipMemsetAsync(counts, 0, (size_t)N*4, stream);
  scatter_k<<<(E+255)/256, 256, 0, stream>>>(esrc, edst, rowptr, counts, psrc, E);

  // layer 1
  gemm_k<128><<<(N+63)/64, 256, 0, stream>>>(x, W1, h12, N, flag, flag);
  al_k<32><<<(4*N+255)/256, 256, 0, stream>>>(h12, as1, ad1, als1, ald1, N, flag);
  agg1<<<(N+3)/4, 256, 0, stream>>>(h12, als1, ald1, b1, rowptr, psrc, hrelu, N, flag);

  // layer 2 (h2 overwrites h1 region; hrelu input is internal bf16 -> flag+1)
  gemm_k<160><<<(N+63)/64, 256, 0, stream>>>(hrelu, W2, h12, N, flag+1, flag);
  al_k<40><<<(4*N+255)/256, 256, 0, stream>>>(h12, as2, ad2, als2, ald2, N, flag);
  agg2<<<(N+3)/4, 256, 0, stream>>>(h12, als2, ald2, b2, rowptr, psrc, d_out, N, flag);
}

// Round 6
// 614.077 us; speedup vs baseline: 1.1555x; 1.1321x over previous
//
#include <hip/hip_runtime.h>

typedef short short8 __attribute__((ext_vector_type(8)));
typedef float f32x4 __attribute__((ext_vector_type(4)));
typedef unsigned short u16;
typedef unsigned int u32;

__device__ __forceinline__ float b2f(u16 u){ union{u32 i; float f;} v; v.i=((u32)u)<<16; return v.f; }
__device__ __forceinline__ u16 f2b(float f){ union{float f; u32 i;} v; v.f=f; return (u16)((v.i + 0x7fffu + ((v.i>>16)&1u))>>16); }
__device__ __forceinline__ float loadv(const void* p, long i, bool isbf){
  return isbf ? b2f(((const u16*)p)[i]) : ((const float*)p)[i];
}
__device__ __forceinline__ float wred(float v){
  v += __shfl_xor(v, 1); v += __shfl_xor(v, 2); v += __shfl_xor(v, 4);
  v += __shfl_xor(v, 8); v += __shfl_xor(v, 16); v += __shfl_xor(v, 32);
  return v;
}

// ---------------- dtype detector: bf16 buffers vs fp32 buffers ----------------
__global__ void detect_bf16(const void* x, int n, int* flag){
  __shared__ int cnt;
  if (threadIdx.x==0) cnt = 0;
  __syncthreads();
  int m = n < 4096 ? n : 4096;
  int good = 0;
  for (int i = threadIdx.x; i < m; i += 256){
    u16 u = ((const u16*)x)[i];
    int e = (u >> 7) & 0xff;
    if (u == 0 || (e >= 100 && e <= 140)) good++;
  }
  atomicAdd(&cnt, good);
  __syncthreads();
  if (threadIdx.x==0){
    flag[0] = (cnt >= (m*3)/4) ? 1 : 0;
    flag[1] = 1;  // constant "is bf16" for internal buffers
  }
}

// ---------------- CSR build ----------------
__global__ void count_k(const int* __restrict__ dst, int* __restrict__ counts, int E){
  int e = blockIdx.x*256 + threadIdx.x;
  if (e < E) atomicAdd(&counts[dst[e]], 1);
}

__global__ __launch_bounds__(256) void scan_bsum(const int* __restrict__ counts, int* __restrict__ bsum, int N){
  __shared__ int sm[256];
  int t = threadIdx.x, i = blockIdx.x*256 + t;
  sm[t] = (i < N) ? counts[i] : 0;
  __syncthreads();
  for (int off = 128; off; off >>= 1){
    if (t < off) sm[t] += sm[t+off];
    __syncthreads();
  }
  if (t == 0) bsum[blockIdx.x] = sm[0];
}

__global__ __launch_bounds__(1024) void scan_top(const int* __restrict__ bsum, int* __restrict__ bscan, int B){
  __shared__ int sm[1024];
  int t = threadIdx.x;
  int v = (t < B) ? bsum[t] : 0;
  sm[t] = v;
  __syncthreads();
  for (int off = 1; off < 1024; off <<= 1){
    int x = (t >= off) ? sm[t-off] : 0;
    __syncthreads();
    sm[t] += x;
    __syncthreads();
  }
  if (t < B) bscan[t] = sm[t] - v;   // exclusive
}

__global__ __launch_bounds__(256) void scan_final(const int* __restrict__ counts, const int* __restrict__ bscan,
                                                  int* __restrict__ rp, int N, int E){
  __shared__ int sm[256];
  int t = threadIdx.x, i = blockIdx.x*256 + t;
  int v = (i < N) ? counts[i] : 0;
  sm[t] = v;
  __syncthreads();
  for (int off = 1; off < 256; off <<= 1){
    int x = (t >= off) ? sm[t-off] : 0;
    __syncthreads();
    sm[t] += x;
    __syncthreads();
  }
  if (i < N) rp[i] = bscan[blockIdx.x] + sm[t] - v;
  if (i == 0) rp[N] = E;
}

__global__ void scatter_k(const int* __restrict__ src, const int* __restrict__ dst,
                          const int* __restrict__ rp, int* __restrict__ cur,
                          int* __restrict__ psrc, int E){
  int e = blockIdx.x*256 + threadIdx.x;
  if (e < E){
    int d = dst[e];
    int pos = rp[d] + atomicAdd(&cur[d], 1);
    psrc[pos] = src[e];
  }
}

// ---------------- GEMM: OUT[N,M] = X[N,128] * W[128,M], bf16 out, fp32 acc ----------------
template<int M>
__global__ __launch_bounds__(256) void gemm_k(const void* __restrict__ X, const void* __restrict__ W,
                                              u16* __restrict__ OUT, int N,
                                              const int* __restrict__ flagX, const int* __restrict__ flagW){
  __shared__ u16 wt[M][136];            // W^T, +8 pad: 2-way bank alias only (free)
  const bool xbf = *flagX != 0;
  const bool wbf = *flagW != 0;
  int tid = threadIdx.x;
  for (int i = tid; i < 128*M; i += 256){
    int k = i / M, c = i % M;
    wt[c][k] = wbf ? ((const u16*)W)[i] : f2b(((const float*)W)[i]);
  }
  __syncthreads();
  int wave = tid >> 6, lane = tid & 63;
  int quad = lane >> 4, l16 = lane & 15;
  int rowbase = blockIdx.x*64 + wave*16;
  int rr = rowbase + l16; if (rr >= N) rr = N-1;
  const int NT = M/16;
  f32x4 acc[NT];
  #pragma unroll
  for (int t=0;t<NT;t++) acc[t] = (f32x4){0.f,0.f,0.f,0.f};
  #pragma unroll
  for (int kt = 0; kt < 4; kt++){
    int kb = kt*32 + quad*8;
    short8 a;
    if (xbf){
      a = *(const short8*)((const u16*)X + (size_t)rr*128 + kb);
    } else {
      const float* xf = (const float*)X + (size_t)rr*128 + kb;
      #pragma unroll
      for (int j=0;j<8;j++) a[j] = (short)f2b(xf[j]);
    }
    #pragma unroll
    for (int t=0;t<NT;t++){
      short8 b = *(const short8*)&wt[t*16 + l16][kb];
      acc[t] = __builtin_amdgcn_mfma_f32_16x16x32_bf16(a, b, acc[t], 0, 0, 0);
    }
  }
  #pragma unroll
  for (int t=0;t<NT;t++){
    #pragma unroll
    for (int r=0;r<4;r++){
      int row = rowbase + quad*4 + r;
      if (row < N) OUT[(size_t)row*M + t*16 + l16] = f2b(acc[t][r]);
    }
  }
}

// ---------------- attention pre-logits: al[n,h] = sum_c h[n,h,c]*a[h,c] ----------------
template<int C>
__global__ __launch_bounds__(256) void al_k(const u16* __restrict__ Hm, const void* __restrict__ as_,
                     const void* __restrict__ ad_,
                     float* __restrict__ als, float* __restrict__ ald, int N, const int* __restrict__ flag){
  __shared__ float s_as[4*C], s_ad[4*C];
  const bool isbf = *flag != 0;
  for (int i = threadIdx.x; i < 4*C; i += 256){
    s_as[i] = loadv(as_, i, isbf);
    s_ad[i] = loadv(ad_, i, isbf);
  }
  __syncthreads();
  int idx = blockIdx.x*256 + threadIdx.x;
  if (idx >= N*4) return;
  int n = idx >> 2, h = idx & 3;
  const short8* row = (const short8*)(Hm + (size_t)n*(4*C) + h*C);
  float ss = 0.f, sd = 0.f;
  #pragma unroll
  for (int v = 0; v < C/8; v++){
    short8 pk = row[v];
    #pragma unroll
    for (int j = 0; j < 8; j++){
      union{u32 i; float f;} u; u.i = ((u32)(u16)pk[j]) << 16;
      ss += u.f * s_as[h*C + v*8 + j];
      sd += u.f * s_ad[h*C + v*8 + j];
    }
  }
  als[idx] = ss;
  ald[idx] = sd;
}

// ---------------- layer-1 aggregation: wave per node ----------------
// Phase A (lane-parallel, per 64-edge chunk): gather als[s] (f32x4), compute 4-head
// exps, stage (row byte-offset, ex[0..3]) in wave-private LDS; accumulate lane-partial
// denominators. Phase B (serial, slim): ds_read offset+ex, u32 row gather, 2 FMA,
// sub-chunks of 4 with hoisted loads.
__global__ __launch_bounds__(256) void agg1(const u16* __restrict__ h1,
    const float* __restrict__ als, const float* __restrict__ ald, const void* __restrict__ b1,
    const int* __restrict__ rp, const int* __restrict__ psrc,
    u16* __restrict__ hrelu, int N, const int* __restrict__ flag){
  __shared__ int   sbuf[4][64];
  __shared__ float exbuf[4][256];
  const bool isbf = *flag != 0;
  int wave = threadIdx.x >> 6, lane = threadIdx.x & 63;
  int node = blockIdx.x*4 + wave;
  bool live = node < N;
  int nd = live ? node : 0;
  int hd = lane >> 4;
  int beg = __builtin_amdgcn_readfirstlane(rp[nd]);
  int end = __builtin_amdgcn_readfirstlane(rp[nd+1]);
  if (!live){ beg = 0; end = 0; }
  f32x4 adv = *(const f32x4*)(ald + nd*4);
  const char* hb = (const char*)h1 + (lane << 2);   // lane's 2-channel (4B) slot
  int* sb = sbuf[wave];
  float* eb = exbuf[wave];
  float a0 = 0.f, a1 = 0.f;
  float sp0 = 0.f, sp1 = 0.f, sp2 = 0.f, sp3 = 0.f;
  for (int cbeg = beg; cbeg < end; cbeg += 64){
    int cnt = min(64, end - cbeg);
    int e = cbeg + lane;
    if (e < end){
      int s = psrc[e];
      f32x4 av = *(const f32x4*)(als + s*4);
      float l0 = av[0]+adv[0], l1 = av[1]+adv[1], l2 = av[2]+adv[2], l3 = av[3]+adv[3];
      l0 = fmaxf(l0, 0.2f*l0); l1 = fmaxf(l1, 0.2f*l1);
      l2 = fmaxf(l2, 0.2f*l2); l3 = fmaxf(l3, 0.2f*l3);
      float e0 = __expf(l0), e1 = __expf(l1), e2 = __expf(l2), e3 = __expf(l3);
      sp0 += e0; sp1 += e1; sp2 += e2; sp3 += e3;
      sb[lane] = s << 8;                       // row byte offset (256 B rows)
      f32x4 ev = {e0, e1, e2, e3};
      *(f32x4*)&eb[lane*4] = ev;
    }
    for (int j0 = 0; j0 < cnt; j0 += 4){
      int off[4]; float ex[4];
      #pragma unroll
      for (int i=0;i<4;i++){
        int jr = j0 + i;
        int jj = jr < cnt ? jr : cnt-1;
        off[i] = sb[jj];
        ex[i]  = jr < cnt ? eb[jj*4 + hd] : 0.f;
      }
      u32 p[4];
      #pragma unroll
      for (int i=0;i<4;i++) p[i] = *(const u32*)(hb + off[i]);
      #pragma unroll
      for (int i=0;i<4;i++){
        union{u32 u; float f;} w;
        w.u = p[i] << 16;         a0 += ex[i]*w.f;
        w.u = p[i] & 0xffff0000u; a1 += ex[i]*w.f;
      }
    }
  }
  float s0 = wred(sp0), s1 = wred(sp1), s2 = wred(sp2), s3 = wred(sp3);
  float sum = hd == 0 ? s0 : hd == 1 ? s1 : hd == 2 ? s2 : s3;
  if (live){
    float inv = 1.f/(sum + 1e-16f);
    float v0 = a0*inv + loadv(b1, 2*lane,     isbf);
    float v1 = a1*inv + loadv(b1, 2*lane + 1, isbf);
    v0 = v0 > 0.f ? v0 : 0.f;
    v1 = v1 > 0.f ? v1 : 0.f;
    u32 packed = (u32)f2b(v0) | ((u32)f2b(v1) << 16);
    *(u32*)(hrelu + (size_t)node*128 + 2*lane) = packed;
  }
}

// ---------------- layer-2 aggregation + head-mean + bias + log_softmax ----------------
__global__ __launch_bounds__(256) void agg2(const u16* __restrict__ h2,
    const float* __restrict__ als, const float* __restrict__ ald, const void* __restrict__ b2,
    const int* __restrict__ rp, const int* __restrict__ psrc,
    void* __restrict__ out, int N, const int* __restrict__ flag){
  __shared__ int   sbuf[4][64];
  __shared__ float exbuf[4][256];
  __shared__ float sm[4][160];
  const bool isbf = *flag != 0;
  int wave = threadIdx.x >> 6, lane = threadIdx.x & 63;
  int node = blockIdx.x*4 + wave;
  bool live = node < N;
  int nd = live ? node : 0;
  int hA = lane / 20;                 // pairA: lane -> channels 2l,2l+1 ; head = pair/20
  bool hasB = lane < 16;              // pairB: 64+lane -> channels 128+2l (head 3)
  int beg = __builtin_amdgcn_readfirstlane(rp[nd]);
  int end = __builtin_amdgcn_readfirstlane(rp[nd+1]);
  if (!live){ beg = 0; end = 0; }
  f32x4 adv = *(const f32x4*)(ald + nd*4);
  const char* hb = (const char*)h2 + (lane << 2);
  int* sb = sbuf[wave];
  float* eb = exbuf[wave];
  float aA0 = 0.f, aA1 = 0.f, aB0 = 0.f, aB1 = 0.f;
  float sp0 = 0.f, sp1 = 0.f, sp2 = 0.f, sp3 = 0.f;
  for (int cbeg = beg; cbeg < end; cbeg += 64){
    int cnt = min(64, end - cbeg);
    int e = cbeg + lane;
    if (e < end){
      int s = psrc[e];
      f32x4 av = *(const f32x4*)(als + s*4);
      float l0 = av[0]+adv[0], l1 = av[1]+adv[1], l2 = av[2]+adv[2], l3 = av[3]+adv[3];
      l0 = fmaxf(l0, 0.2f*l0); l1 = fmaxf(l1, 0.2f*l1);
      l2 = fmaxf(l2, 0.2f*l2); l3 = fmaxf(l3, 0.2f*l3);
      float e0 = __expf(l0), e1 = __expf(l1), e2 = __expf(l2), e3 = __expf(l3);
      sp0 += e0; sp1 += e1; sp2 += e2; sp3 += e3;
      sb[lane] = s * 320;                      // row byte offset (320 B rows)
      f32x4 ev = {e0, e1, e2, e3};
      *(f32x4*)&eb[lane*4] = ev;
    }
    for (int j0 = 0; j0 < cnt; j0 += 4){
      int off[4]; float exA[4], exB[4];
      #pragma unroll
      for (int i=0;i<4;i++){
        int jr = j0 + i;
        int jj = jr < cnt ? jr : cnt-1;
        off[i] = sb[jj];
        exA[i] = jr < cnt ? eb[jj*4 + hA] : 0.f;
        exB[i] = jr < cnt ? eb[jj*4 + 3]  : 0.f;
      }
      u32 p[4], q[4];
      #pragma unroll
      for (int i=0;i<4;i++){
        p[i] = *(const u32*)(hb + off[i]);
        if (hasB) q[i] = *(const u32*)(hb + off[i] + 256);
      }
      #pragma unroll
      for (int i=0;i<4;i++){
        union{u32 u; float f;} w;
        w.u = p[i] << 16;         aA0 += exA[i]*w.f;
        w.u = p[i] & 0xffff0000u; aA1 += exA[i]*w.f;
        if (hasB){
          w.u = q[i] << 16;         aB0 += exB[i]*w.f;
          w.u = q[i] & 0xffff0000u; aB1 += exB[i]*w.f;
        }
      }
    }
  }
  float s0 = wred(sp0), s1 = wred(sp1), s2 = wred(sp2), s3 = wred(sp3);
  float sumA = hA == 0 ? s0 : hA == 1 ? s1 : hA == 2 ? s2 : s3;
  float invA = 1.f/(sumA + 1e-16f);
  sm[wave][2*lane]     = aA0*invA;
  sm[wave][2*lane + 1] = aA1*invA;
  if (hasB){
    float invB = 1.f/(s3 + 1e-16f);
    sm[wave][128 + 2*lane] = aB0*invB;
    sm[wave][129 + 2*lane] = aB1*invB;
  }
  __syncthreads();
  float v = -__builtin_inff();
  if (lane < 40)
    v = (sm[wave][lane] + sm[wave][40+lane] + sm[wave][80+lane] + sm[wave][120+lane]) * 0.25f
        + loadv(b2, lane, isbf);
  float mxo = v;
  for (int o = 32; o; o >>= 1) mxo = fmaxf(mxo, __shfl_xor(mxo, o));
  float ex = (lane < 40) ? __expf(v - mxo) : 0.f;
  float S = ex;
  for (int o = 32; o; o >>= 1) S += __shfl_xor(S, o);
  if (live && lane < 40){
    float r = v - mxo - __logf(S);
    if (isbf) ((u16*)out)[(size_t)node*40 + lane] = f2b(r);
    else      ((float*)out)[(size_t)node*40 + lane] = r;
  }
}

extern "C" void kernel_launch(void* const* d_in, const int* in_sizes, int n_in,
                              void* d_out, int out_size, void* d_ws, size_t ws_size,
                              hipStream_t stream){
  const void* x   = d_in[0];
  const int*  ei  = (const int*)d_in[1];
  const void* W1  = d_in[2];
  const void* as1 = d_in[3];
  const void* ad1 = d_in[4];
  const void* b1  = d_in[5];
  const void* W2  = d_in[6];
  const void* as2 = d_in[7];
  const void* ad2 = d_in[8];
  const void* b2  = d_in[9];

  const int N = in_sizes[0] / 128;
  const int E = in_sizes[1] / 2;
  const int* esrc = ei;
  const int* edst = ei + E;

  char* w = (char*)d_ws;
  size_t off = 0;
  auto take = [&](size_t bytes)->void*{
    void* p = w + off;
    off = (off + bytes + 255) & ~(size_t)255;
    return p;
  };
  u16*   h12    = (u16*)take((size_t)N*160*2);   // h1 [N,128] then h2 [N,160] (aliased)
  u16*   hrelu  = (u16*)take((size_t)N*128*2);
  float* als1   = (float*)take((size_t)N*4*4);
  float* ald1   = (float*)take((size_t)N*4*4);
  float* als2   = (float*)take((size_t)N*4*4);
  float* ald2   = (float*)take((size_t)N*4*4);
  int*   rowptr = (int*)take((size_t)(N+1)*4);
  int*   counts = (int*)take((size_t)N*4);
  int*   bsum   = (int*)take(1024*4);
  int*   bscan  = (int*)take(1024*4);
  int*   psrc   = (int*)take((size_t)E*4);
  int*   flag   = (int*)take(64);

  const int B = (N + 255) / 256;

  detect_bf16<<<1, 256, 0, stream>>>(x, N*128, flag);

  // CSR by dst
  hipMemsetAsync(counts, 0, (size_t)N*4, stream);
  count_k<<<(E+255)/256, 256, 0, stream>>>(edst, counts, E);
  scan_bsum<<<B, 256, 0, stream>>>(counts, bsum, N);
  scan_top<<<1, 1024, 0, stream>>>(bsum, bscan, B);
  scan_final<<<B, 256, 0, stream>>>(counts, bscan, rowptr, N, E);
  hipMemsetAsync(counts, 0, (size_t)N*4, stream);
  scatter_k<<<(E+255)/256, 256, 0, stream>>>(esrc, edst, rowptr, counts, psrc, E);

  // layer 1
  gemm_k<128><<<(N+63)/64, 256, 0, stream>>>(x, W1, h12, N, flag, flag);
  al_k<32><<<(4*N+255)/256, 256, 0, stream>>>(h12, as1, ad1, als1, ald1, N, flag);
  agg1<<<(N+3)/4, 256, 0, stream>>>(h12, als1, ald1, b1, rowptr, psrc, hrelu, N, flag);

  // layer 2 (h2 overwrites h1 region; hrelu input is internal bf16 -> flag+1)
  gemm_k<160><<<(N+63)/64, 256, 0, stream>>>(hrelu, W2, h12, N, flag+1, flag);
  al_k<40><<<(4*N+255)/256, 256, 0, stream>>>(h12, as2, ad2, als2, ald2, N, flag);
  agg2<<<(N+3)/4, 256, 0, stream>>>(h12, als2, ald2, b2, rowptr, psrc, d_out, N, flag);
}

// Round 7
// 572.419 us; speedup vs baseline: 1.2396x; 1.0728x over previous
//
#include <hip/hip_runtime.h>

typedef short short8 __attribute__((ext_vector_type(8)));
typedef float f32x4 __attribute__((ext_vector_type(4)));
typedef unsigned short u16;
typedef unsigned int u32;

__device__ __forceinline__ float b2f(u16 u){ union{u32 i; float f;} v; v.i=((u32)u)<<16; return v.f; }
__device__ __forceinline__ u16 f2b(float f){ union{float f; u32 i;} v; v.f=f; return (u16)((v.i + 0x7fffu + ((v.i>>16)&1u))>>16); }
__device__ __forceinline__ float loadv(const void* p, long i, bool isbf){
  return isbf ? b2f(((const u16*)p)[i]) : ((const float*)p)[i];
}
__device__ __forceinline__ float wred(float v){
  v += __shfl_xor(v, 1); v += __shfl_xor(v, 2); v += __shfl_xor(v, 4);
  v += __shfl_xor(v, 8); v += __shfl_xor(v, 16); v += __shfl_xor(v, 32);
  return v;
}

// ---------------- dtype detector: bf16 buffers vs fp32 buffers ----------------
__global__ void detect_bf16(const void* x, int n, int* flag){
  __shared__ int cnt;
  if (threadIdx.x==0) cnt = 0;
  __syncthreads();
  int m = n < 4096 ? n : 4096;
  int good = 0;
  for (int i = threadIdx.x; i < m; i += 256){
    u16 u = ((const u16*)x)[i];
    int e = (u >> 7) & 0xff;
    if (u == 0 || (e >= 100 && e <= 140)) good++;
  }
  atomicAdd(&cnt, good);
  __syncthreads();
  if (threadIdx.x==0){
    flag[0] = (cnt >= (m*3)/4) ? 1 : 0;
    flag[1] = 1;  // constant "is bf16" for internal buffers
  }
}

// ---------------- CSR build, XCD-partitioned ----------------
// region = blockIdx & 7 (presumed round-robin block->XCD); each region-group
// streams the whole edge list but touches only its node range -> counts/cur/psrc
// lines are written by a single XCD -> full-line dirty eviction, no cross-XCD
// partial-line write amplification.
__global__ __launch_bounds__(256) void count_x(const int* __restrict__ dst,
    int* __restrict__ counts, int E, int N, int nchunk){
  int r = blockIdx.x & 7;
  int chunk = blockIdx.x >> 3;
  int lo = (int)(((long)N * r) >> 3);
  int hi = (int)(((long)N * (r+1)) >> 3);
  int per = (E + nchunk - 1) / nchunk;
  int s = chunk * per, t = min(E, s + per);
  for (int e = s + threadIdx.x; e < t; e += 256){
    int d = dst[e];
    if (d >= lo && d < hi) atomicAdd(&counts[d], 1);
  }
}

__global__ __launch_bounds__(256) void scatter_x(const int* __restrict__ src, const int* __restrict__ dst,
    const int* __restrict__ rp, int* __restrict__ cur,
    int* __restrict__ psrc, int E, int N, int nchunk){
  int r = blockIdx.x & 7;
  int chunk = blockIdx.x >> 3;
  int lo = (int)(((long)N * r) >> 3);
  int hi = (int)(((long)N * (r+1)) >> 3);
  int per = (E + nchunk - 1) / nchunk;
  int s = chunk * per, t = min(E, s + per);
  for (int e = s + threadIdx.x; e < t; e += 256){
    int d = dst[e];
    if (d >= lo && d < hi){
      int pos = rp[d] + atomicAdd(&cur[d], 1);
      psrc[pos] = src[e];
    }
  }
}

__global__ __launch_bounds__(256) void scan_bsum(const int* __restrict__ counts, int* __restrict__ bsum, int N){
  __shared__ int sm[256];
  int t = threadIdx.x, i = blockIdx.x*256 + t;
  sm[t] = (i < N) ? counts[i] : 0;
  __syncthreads();
  for (int off = 128; off; off >>= 1){
    if (t < off) sm[t] += sm[t+off];
    __syncthreads();
  }
  if (t == 0) bsum[blockIdx.x] = sm[0];
}

__global__ __launch_bounds__(1024) void scan_top(const int* __restrict__ bsum, int* __restrict__ bscan, int B){
  __shared__ int sm[1024];
  int t = threadIdx.x;
  int v = (t < B) ? bsum[t] : 0;
  sm[t] = v;
  __syncthreads();
  for (int off = 1; off < 1024; off <<= 1){
    int x = (t >= off) ? sm[t-off] : 0;
    __syncthreads();
    sm[t] += x;
    __syncthreads();
  }
  if (t < B) bscan[t] = sm[t] - v;   // exclusive
}

__global__ __launch_bounds__(256) void scan_final(const int* __restrict__ counts, const int* __restrict__ bscan,
                                                  int* __restrict__ rp, int N, int E){
  __shared__ int sm[256];
  int t = threadIdx.x, i = blockIdx.x*256 + t;
  int v = (i < N) ? counts[i] : 0;
  sm[t] = v;
  __syncthreads();
  for (int off = 1; off < 256; off <<= 1){
    int x = (t >= off) ? sm[t-off] : 0;
    __syncthreads();
    sm[t] += x;
    __syncthreads();
  }
  if (i < N) rp[i] = bscan[blockIdx.x] + sm[t] - v;
  if (i == 0) rp[N] = E;
}

// ---------------- GEMM: OUT[N,M] = X[N,128] * W[128,M], bf16 out, fp32 acc ----------------
template<int M>
__global__ __launch_bounds__(256) void gemm_k(const void* __restrict__ X, const void* __restrict__ W,
                                              u16* __restrict__ OUT, int N,
                                              const int* __restrict__ flagX, const int* __restrict__ flagW){
  __shared__ u16 wt[M][136];            // W^T, +8 pad: 2-way bank alias only (free)
  const bool xbf = *flagX != 0;
  const bool wbf = *flagW != 0;
  int tid = threadIdx.x;
  for (int i = tid; i < 128*M; i += 256){
    int k = i / M, c = i % M;
    wt[c][k] = wbf ? ((const u16*)W)[i] : f2b(((const float*)W)[i]);
  }
  __syncthreads();
  int wave = tid >> 6, lane = tid & 63;
  int quad = lane >> 4, l16 = lane & 15;
  int rowbase = blockIdx.x*64 + wave*16;
  int rr = rowbase + l16; if (rr >= N) rr = N-1;
  const int NT = M/16;
  f32x4 acc[NT];
  #pragma unroll
  for (int t=0;t<NT;t++) acc[t] = (f32x4){0.f,0.f,0.f,0.f};
  #pragma unroll
  for (int kt = 0; kt < 4; kt++){
    int kb = kt*32 + quad*8;
    short8 a;
    if (xbf){
      a = *(const short8*)((const u16*)X + (size_t)rr*128 + kb);
    } else {
      const float* xf = (const float*)X + (size_t)rr*128 + kb;
      #pragma unroll
      for (int j=0;j<8;j++) a[j] = (short)f2b(xf[j]);
    }
    #pragma unroll
    for (int t=0;t<NT;t++){
      short8 b = *(const short8*)&wt[t*16 + l16][kb];
      acc[t] = __builtin_amdgcn_mfma_f32_16x16x32_bf16(a, b, acc[t], 0, 0, 0);
    }
  }
  #pragma unroll
  for (int t=0;t<NT;t++){
    #pragma unroll
    for (int r=0;r<4;r++){
      int row = rowbase + quad*4 + r;
      if (row < N) OUT[(size_t)row*M + t*16 + l16] = f2b(acc[t][r]);
    }
  }
}

// ---------------- attention pre-logits: al[n,h] = sum_c h[n,h,c]*a[h,c] ----------------
template<int C>
__global__ __launch_bounds__(256) void al_k(const u16* __restrict__ Hm, const void* __restrict__ as_,
                     const void* __restrict__ ad_,
                     float* __restrict__ als, float* __restrict__ ald, int N, const int* __restrict__ flag){
  __shared__ float s_as[4*C], s_ad[4*C];
  const bool isbf = *flag != 0;
  for (int i = threadIdx.x; i < 4*C; i += 256){
    s_as[i] = loadv(as_, i, isbf);
    s_ad[i] = loadv(ad_, i, isbf);
  }
  __syncthreads();
  int idx = blockIdx.x*256 + threadIdx.x;
  if (idx >= N*4) return;
  int n = idx >> 2, h = idx & 3;
  const short8* row = (const short8*)(Hm + (size_t)n*(4*C) + h*C);
  float ss = 0.f, sd = 0.f;
  #pragma unroll
  for (int v = 0; v < C/8; v++){
    short8 pk = row[v];
    #pragma unroll
    for (int j = 0; j < 8; j++){
      union{u32 i; float f;} u; u.i = ((u32)(u16)pk[j]) << 16;
      ss += u.f * s_as[h*C + v*8 + j];
      sd += u.f * s_ad[h*C + v*8 + j];
    }
  }
  als[idx] = ss;
  ald[idx] = sd;
}

// ---------------- layer-1 aggregation: wave per node ----------------
__global__ __launch_bounds__(256) void agg1(const u16* __restrict__ h1,
    const float* __restrict__ als, const float* __restrict__ ald, const void* __restrict__ b1,
    const int* __restrict__ rp, const int* __restrict__ psrc,
    u16* __restrict__ hrelu, int N, const int* __restrict__ flag){
  __shared__ int   sbuf[4][64];
  __shared__ float exbuf[4][256];
  const bool isbf = *flag != 0;
  int wave = threadIdx.x >> 6, lane = threadIdx.x & 63;
  int node = blockIdx.x*4 + wave;
  bool live = node < N;
  int nd = live ? node : 0;
  int hd = lane >> 4;
  int beg = __builtin_amdgcn_readfirstlane(rp[nd]);
  int end = __builtin_amdgcn_readfirstlane(rp[nd+1]);
  if (!live){ beg = 0; end = 0; }
  f32x4 adv = *(const f32x4*)(ald + nd*4);
  const char* hb = (const char*)h1 + (lane << 2);   // lane's 2-channel (4B) slot
  int* sb = sbuf[wave];
  float* eb = exbuf[wave];
  float a0 = 0.f, a1 = 0.f;
  float sp0 = 0.f, sp1 = 0.f, sp2 = 0.f, sp3 = 0.f;
  for (int cbeg = beg; cbeg < end; cbeg += 64){
    int cnt = min(64, end - cbeg);
    int e = cbeg + lane;
    if (e < end){
      int s = psrc[e];
      f32x4 av = *(const f32x4*)(als + s*4);
      float l0 = av[0]+adv[0], l1 = av[1]+adv[1], l2 = av[2]+adv[2], l3 = av[3]+adv[3];
      l0 = fmaxf(l0, 0.2f*l0); l1 = fmaxf(l1, 0.2f*l1);
      l2 = fmaxf(l2, 0.2f*l2); l3 = fmaxf(l3, 0.2f*l3);
      float e0 = __expf(l0), e1 = __expf(l1), e2 = __expf(l2), e3 = __expf(l3);
      sp0 += e0; sp1 += e1; sp2 += e2; sp3 += e3;
      sb[lane] = s << 8;                       // row byte offset (256 B rows)
      f32x4 ev = {e0, e1, e2, e3};
      *(f32x4*)&eb[lane*4] = ev;
    }
    for (int j0 = 0; j0 < cnt; j0 += 4){
      int off[4]; float ex[4];
      #pragma unroll
      for (int i=0;i<4;i++){
        int jr = j0 + i;
        int jj = jr < cnt ? jr : cnt-1;
        off[i] = sb[jj];
        ex[i]  = jr < cnt ? eb[jj*4 + hd] : 0.f;
      }
      u32 p[4];
      #pragma unroll
      for (int i=0;i<4;i++) p[i] = *(const u32*)(hb + off[i]);
      #pragma unroll
      for (int i=0;i<4;i++){
        union{u32 u; float f;} w;
        w.u = p[i] << 16;         a0 += ex[i]*w.f;
        w.u = p[i] & 0xffff0000u; a1 += ex[i]*w.f;
      }
    }
  }
  float s0 = wred(sp0), s1 = wred(sp1), s2 = wred(sp2), s3 = wred(sp3);
  float sum = hd == 0 ? s0 : hd == 1 ? s1 : hd == 2 ? s2 : s3;
  if (live){
    float inv = 1.f/(sum + 1e-16f);
    float v0 = a0*inv + loadv(b1, 2*lane,     isbf);
    float v1 = a1*inv + loadv(b1, 2*lane + 1, isbf);
    v0 = v0 > 0.f ? v0 : 0.f;
    v1 = v1 > 0.f ? v1 : 0.f;
    u32 packed = (u32)f2b(v0) | ((u32)f2b(v1) << 16);
    *(u32*)(hrelu + (size_t)node*128 + 2*lane) = packed;
  }
}

// ---------------- layer-2 aggregation + head-mean + bias + log_softmax ----------------
__global__ __launch_bounds__(256) void agg2(const u16* __restrict__ h2,
    const float* __restrict__ als, const float* __restrict__ ald, const void* __restrict__ b2,
    const int* __restrict__ rp, const int* __restrict__ psrc,
    void* __restrict__ out, int N, const int* __restrict__ flag){
  __shared__ int   sbuf[4][64];
  __shared__ float exbuf[4][256];
  __shared__ float sm[4][160];
  const bool isbf = *flag != 0;
  int wave = threadIdx.x >> 6, lane = threadIdx.x & 63;
  int node = blockIdx.x*4 + wave;
  bool live = node < N;
  int nd = live ? node : 0;
  int hA = lane / 20;                 // pairA: lane -> channels 2l,2l+1 ; head = pair/20
  bool hasB = lane < 16;              // pairB: 64+lane -> channels 128+2l (head 3)
  int beg = __builtin_amdgcn_readfirstlane(rp[nd]);
  int end = __builtin_amdgcn_readfirstlane(rp[nd+1]);
  if (!live){ beg = 0; end = 0; }
  f32x4 adv = *(const f32x4*)(ald + nd*4);
  const char* hb = (const char*)h2 + (lane << 2);
  int* sb = sbuf[wave];
  float* eb = exbuf[wave];
  float aA0 = 0.f, aA1 = 0.f, aB0 = 0.f, aB1 = 0.f;
  float sp0 = 0.f, sp1 = 0.f, sp2 = 0.f, sp3 = 0.f;
  for (int cbeg = beg; cbeg < end; cbeg += 64){
    int cnt = min(64, end - cbeg);
    int e = cbeg + lane;
    if (e < end){
      int s = psrc[e];
      f32x4 av = *(const f32x4*)(als + s*4);
      float l0 = av[0]+adv[0], l1 = av[1]+adv[1], l2 = av[2]+adv[2], l3 = av[3]+adv[3];
      l0 = fmaxf(l0, 0.2f*l0); l1 = fmaxf(l1, 0.2f*l1);
      l2 = fmaxf(l2, 0.2f*l2); l3 = fmaxf(l3, 0.2f*l3);
      float e0 = __expf(l0), e1 = __expf(l1), e2 = __expf(l2), e3 = __expf(l3);
      sp0 += e0; sp1 += e1; sp2 += e2; sp3 += e3;
      sb[lane] = s * 320;                      // row byte offset (320 B rows)
      f32x4 ev = {e0, e1, e2, e3};
      *(f32x4*)&eb[lane*4] = ev;
    }
    for (int j0 = 0; j0 < cnt; j0 += 4){
      int off[4]; float exA[4], exB[4];
      #pragma unroll
      for (int i=0;i<4;i++){
        int jr = j0 + i;
        int jj = jr < cnt ? jr : cnt-1;
        off[i] = sb[jj];
        exA[i] = jr < cnt ? eb[jj*4 + hA] : 0.f;
        exB[i] = jr < cnt ? eb[jj*4 + 3]  : 0.f;
      }
      u32 p[4], q[4];
      #pragma unroll
      for (int i=0;i<4;i++){
        p[i] = *(const u32*)(hb + off[i]);
        if (hasB) q[i] = *(const u32*)(hb + off[i] + 256);
      }
      #pragma unroll
      for (int i=0;i<4;i++){
        union{u32 u; float f;} w;
        w.u = p[i] << 16;         aA0 += exA[i]*w.f;
        w.u = p[i] & 0xffff0000u; aA1 += exA[i]*w.f;
        if (hasB){
          w.u = q[i] << 16;         aB0 += exB[i]*w.f;
          w.u = q[i] & 0xffff0000u; aB1 += exB[i]*w.f;
        }
      }
    }
  }
  float s0 = wred(sp0), s1 = wred(sp1), s2 = wred(sp2), s3 = wred(sp3);
  float sumA = hA == 0 ? s0 : hA == 1 ? s1 : hA == 2 ? s2 : s3;
  float invA = 1.f/(sumA + 1e-16f);
  sm[wave][2*lane]     = aA0*invA;
  sm[wave][2*lane + 1] = aA1*invA;
  if (hasB){
    float invB = 1.f/(s3 + 1e-16f);
    sm[wave][128 + 2*lane] = aB0*invB;
    sm[wave][129 + 2*lane] = aB1*invB;
  }
  __syncthreads();
  float v = -__builtin_inff();
  if (lane < 40)
    v = (sm[wave][lane] + sm[wave][40+lane] + sm[wave][80+lane] + sm[wave][120+lane]) * 0.25f
        + loadv(b2, lane, isbf);
  float mxo = v;
  for (int o = 32; o; o >>= 1) mxo = fmaxf(mxo, __shfl_xor(mxo, o));
  float ex = (lane < 40) ? __expf(v - mxo) : 0.f;
  float S = ex;
  for (int o = 32; o; o >>= 1) S += __shfl_xor(S, o);
  if (live && lane < 40){
    float r = v - mxo - __logf(S);
    if (isbf) ((u16*)out)[(size_t)node*40 + lane] = f2b(r);
    else      ((float*)out)[(size_t)node*40 + lane] = r;
  }
}

extern "C" void kernel_launch(void* const* d_in, const int* in_sizes, int n_in,
                              void* d_out, int out_size, void* d_ws, size_t ws_size,
                              hipStream_t stream){
  const void* x   = d_in[0];
  const int*  ei  = (const int*)d_in[1];
  const void* W1  = d_in[2];
  const void* as1 = d_in[3];
  const void* ad1 = d_in[4];
  const void* b1  = d_in[5];
  const void* W2  = d_in[6];
  const void* as2 = d_in[7];
  const void* ad2 = d_in[8];
  const void* b2  = d_in[9];

  const int N = in_sizes[0] / 128;
  const int E = in_sizes[1] / 2;
  const int* esrc = ei;
  const int* edst = ei + E;

  char* w = (char*)d_ws;
  size_t off = 0;
  auto take = [&](size_t bytes)->void*{
    void* p = w + off;
    off = (off + bytes + 255) & ~(size_t)255;
    return p;
  };
  u16*   h12    = (u16*)take((size_t)N*160*2);   // h1 [N,128] then h2 [N,160] (aliased)
  u16*   hrelu  = (u16*)take((size_t)N*128*2);
  float* als1   = (float*)take((size_t)N*4*4);
  float* ald1   = (float*)take((size_t)N*4*4);
  float* als2   = (float*)take((size_t)N*4*4);
  float* ald2   = (float*)take((size_t)N*4*4);
  int*   rowptr = (int*)take((size_t)(N+1)*4);
  int*   counts = (int*)take((size_t)N*4);
  int*   bsum   = (int*)take(1024*4);
  int*   bscan  = (int*)take(1024*4);
  int*   psrc   = (int*)take((size_t)E*4);
  int*   flag   = (int*)take(64);

  const int B = (N + 255) / 256;
  const int NCHUNK = 128;               // blocks per region-group; grid = 8*NCHUNK

  detect_bf16<<<1, 256, 0, stream>>>(x, N*128, flag);

  // CSR by dst (XCD-partitioned count & scatter)
  hipMemsetAsync(counts, 0, (size_t)N*4, stream);
  count_x<<<8*NCHUNK, 256, 0, stream>>>(edst, counts, E, N, NCHUNK);
  scan_bsum<<<B, 256, 0, stream>>>(counts, bsum, N);
  scan_top<<<1, 1024, 0, stream>>>(bsum, bscan, B);
  scan_final<<<B, 256, 0, stream>>>(counts, bscan, rowptr, N, E);
  hipMemsetAsync(counts, 0, (size_t)N*4, stream);
  scatter_x<<<8*NCHUNK, 256, 0, stream>>>(esrc, edst, rowptr, counts, psrc, E, N, NCHUNK);

  // layer 1
  gemm_k<128><<<(N+63)/64, 256, 0, stream>>>(x, W1, h12, N, flag, flag);
  al_k<32><<<(4*N+255)/256, 256, 0, stream>>>(h12, as1, ad1, als1, ald1, N, flag);
  agg1<<<(N+3)/4, 256, 0, stream>>>(h12, als1, ald1, b1, rowptr, psrc, hrelu, N, flag);

  // layer 2 (h2 overwrites h1 region; hrelu input is internal bf16 -> flag+1)
  gemm_k<160><<<(N+63)/64, 256, 0, stream>>>(hrelu, W2, h12, N, flag+1, flag);
  al_k<40><<<(4*N+255)/256, 256, 0, stream>>>(h12, as2, ad2, als2, ald2, N, flag);
  agg2<<<(N+3)/4, 256, 0, stream>>>(h12, als2, ald2, b2, rowptr, psrc, d_out, N, flag);
}

// Round 8
// 568.935 us; speedup vs baseline: 1.2471x; 1.0061x over previous
//
#include <hip/hip_runtime.h>

typedef short short8 __attribute__((ext_vector_type(8)));
typedef float f32x4 __attribute__((ext_vector_type(4)));
typedef int   i32x4 __attribute__((ext_vector_type(4)));
typedef unsigned short u16;
typedef unsigned int u32;

__device__ __forceinline__ float b2f(u16 u){ union{u32 i; float f;} v; v.i=((u32)u)<<16; return v.f; }
__device__ __forceinline__ u16 f2b(float f){ union{float f; u32 i;} v; v.f=f; return (u16)((v.i + 0x7fffu + ((v.i>>16)&1u))>>16); }
__device__ __forceinline__ float loadv(const void* p, long i, bool isbf){
  return isbf ? b2f(((const u16*)p)[i]) : ((const float*)p)[i];
}
__device__ __forceinline__ float wred(float v){
  v += __shfl_xor(v, 1); v += __shfl_xor(v, 2); v += __shfl_xor(v, 4);
  v += __shfl_xor(v, 8); v += __shfl_xor(v, 16); v += __shfl_xor(v, 32);
  return v;
}

// ---------------- dtype detector: bf16 buffers vs fp32 buffers ----------------
__global__ void detect_bf16(const void* x, int n, int* flag){
  __shared__ int cnt;
  if (threadIdx.x==0) cnt = 0;
  __syncthreads();
  int m = n < 4096 ? n : 4096;
  int good = 0;
  for (int i = threadIdx.x; i < m; i += 256){
    u16 u = ((const u16*)x)[i];
    int e = (u >> 7) & 0xff;
    if (u == 0 || (e >= 100 && e <= 140)) good++;
  }
  atomicAdd(&cnt, good);
  __syncthreads();
  if (threadIdx.x==0){
    flag[0] = (cnt >= (m*3)/4) ? 1 : 0;
    flag[1] = 1;  // constant "is bf16" for internal buffers
  }
}

// ---------------- CSR build, XCD-partitioned ----------------
__global__ __launch_bounds__(256) void count_x(const int* __restrict__ dst,
    int* __restrict__ counts, int E, int N, int nchunk){
  int r = blockIdx.x & 7;
  int chunk = blockIdx.x >> 3;
  int lo = (int)(((long)N * r) >> 3);
  int hi = (int)(((long)N * (r+1)) >> 3);
  int per = (E + nchunk - 1) / nchunk;
  int s = chunk * per, t = min(E, s + per);
  for (int e = s + threadIdx.x; e < t; e += 256){
    int d = dst[e];
    if (d >= lo && d < hi) atomicAdd(&counts[d], 1);
  }
}

__global__ __launch_bounds__(256) void scatter_x(const int* __restrict__ src, const int* __restrict__ dst,
    const int* __restrict__ rp, int* __restrict__ cur,
    int* __restrict__ psrc, int E, int N, int nchunk){
  int r = blockIdx.x & 7;
  int chunk = blockIdx.x >> 3;
  int lo = (int)(((long)N * r) >> 3);
  int hi = (int)(((long)N * (r+1)) >> 3);
  int per = (E + nchunk - 1) / nchunk;
  int s = chunk * per, t = min(E, s + per);
  for (int e = s + threadIdx.x; e < t; e += 256){
    int d = dst[e];
    if (d >= lo && d < hi){
      int pos = rp[d] + atomicAdd(&cur[d], 1);
      psrc[pos] = src[e];
    }
  }
}

__global__ __launch_bounds__(256) void scan_bsum(const int* __restrict__ counts, int* __restrict__ bsum, int N){
  __shared__ int sm[256];
  int t = threadIdx.x, i = blockIdx.x*256 + t;
  sm[t] = (i < N) ? counts[i] : 0;
  __syncthreads();
  for (int off = 128; off; off >>= 1){
    if (t < off) sm[t] += sm[t+off];
    __syncthreads();
  }
  if (t == 0) bsum[blockIdx.x] = sm[0];
}

__global__ __launch_bounds__(1024) void scan_top(const int* __restrict__ bsum, int* __restrict__ bscan, int B){
  __shared__ int sm[1024];
  int t = threadIdx.x;
  int v = (t < B) ? bsum[t] : 0;
  sm[t] = v;
  __syncthreads();
  for (int off = 1; off < 1024; off <<= 1){
    int x = (t >= off) ? sm[t-off] : 0;
    __syncthreads();
    sm[t] += x;
    __syncthreads();
  }
  if (t < B) bscan[t] = sm[t] - v;   // exclusive
}

__global__ __launch_bounds__(256) void scan_final(const int* __restrict__ counts, const int* __restrict__ bscan,
                                                  int* __restrict__ rp, int N, int E){
  __shared__ int sm[256];
  int t = threadIdx.x, i = blockIdx.x*256 + t;
  int v = (i < N) ? counts[i] : 0;
  sm[t] = v;
  __syncthreads();
  for (int off = 1; off < 256; off <<= 1){
    int x = (t >= off) ? sm[t-off] : 0;
    __syncthreads();
    sm[t] += x;
    __syncthreads();
  }
  if (i < N) rp[i] = bscan[blockIdx.x] + sm[t] - v;
  if (i == 0) rp[N] = E;
}

// ---------------- GEMM: OUT[N,M] = X[N,128] * W[128,M], bf16 out, fp32 acc ----------------
template<int M>
__global__ __launch_bounds__(256) void gemm_k(const void* __restrict__ X, const void* __restrict__ W,
                                              u16* __restrict__ OUT, int N,
                                              const int* __restrict__ flagX, const int* __restrict__ flagW){
  __shared__ u16 wt[M][136];            // W^T, +8 pad: 2-way bank alias only (free)
  const bool xbf = *flagX != 0;
  const bool wbf = *flagW != 0;
  int tid = threadIdx.x;
  for (int i = tid; i < 128*M; i += 256){
    int k = i / M, c = i % M;
    wt[c][k] = wbf ? ((const u16*)W)[i] : f2b(((const float*)W)[i]);
  }
  __syncthreads();
  int wave = tid >> 6, lane = tid & 63;
  int quad = lane >> 4, l16 = lane & 15;
  int rowbase = blockIdx.x*64 + wave*16;
  int rr = rowbase + l16; if (rr >= N) rr = N-1;
  const int NT = M/16;
  f32x4 acc[NT];
  #pragma unroll
  for (int t=0;t<NT;t++) acc[t] = (f32x4){0.f,0.f,0.f,0.f};
  #pragma unroll
  for (int kt = 0; kt < 4; kt++){
    int kb = kt*32 + quad*8;
    short8 a;
    if (xbf){
      a = *(const short8*)((const u16*)X + (size_t)rr*128 + kb);
    } else {
      const float* xf = (const float*)X + (size_t)rr*128 + kb;
      #pragma unroll
      for (int j=0;j<8;j++) a[j] = (short)f2b(xf[j]);
    }
    #pragma unroll
    for (int t=0;t<NT;t++){
      short8 b = *(const short8*)&wt[t*16 + l16][kb];
      acc[t] = __builtin_amdgcn_mfma_f32_16x16x32_bf16(a, b, acc[t], 0, 0, 0);
    }
  }
  #pragma unroll
  for (int t=0;t<NT;t++){
    #pragma unroll
    for (int r=0;r<4;r++){
      int row = rowbase + quad*4 + r;
      if (row < N) OUT[(size_t)row*M + t*16 + l16] = f2b(acc[t][r]);
    }
  }
}

// ---------------- attention pre-logits: al[n,h] = sum_c h[n,h,c]*a[h,c] ----------------
template<int C>
__global__ __launch_bounds__(256) void al_k(const u16* __restrict__ Hm, const void* __restrict__ as_,
                     const void* __restrict__ ad_,
                     float* __restrict__ als, float* __restrict__ ald, int N, const int* __restrict__ flag){
  __shared__ float s_as[4*C], s_ad[4*C];
  const bool isbf = *flag != 0;
  for (int i = threadIdx.x; i < 4*C; i += 256){
    s_as[i] = loadv(as_, i, isbf);
    s_ad[i] = loadv(ad_, i, isbf);
  }
  __syncthreads();
  int idx = blockIdx.x*256 + threadIdx.x;
  if (idx >= N*4) return;
  int n = idx >> 2, h = idx & 3;
  const short8* row = (const short8*)(Hm + (size_t)n*(4*C) + h*C);
  float ss = 0.f, sd = 0.f;
  #pragma unroll
  for (int v = 0; v < C/8; v++){
    short8 pk = row[v];
    #pragma unroll
    for (int j = 0; j < 8; j++){
      union{u32 i; float f;} u; u.i = ((u32)(u16)pk[j]) << 16;
      ss += u.f * s_as[h*C + v*8 + j];
      sd += u.f * s_ad[h*C + v*8 + j];
    }
  }
  als[idx] = ss;
  ald[idx] = sd;
}

// ---------------- layer-1 aggregation: wave per node ----------------
// Phase A: lane-parallel exp into transposed LDS ebT[head][edge] (stride 68 -> 4
// head-groups' b128 reads hit disjoint banks); pad chunk to multiple of 4 with
// ex=0/off=0 (adds exactly 0 to sums). Phase B: per 4 edges = 2x ds_read_b128 +
// 4 saddr-form gathers + unpack/FMA. No per-edge compares.
__global__ __launch_bounds__(256) void agg1(const u16* __restrict__ h1,
    const float* __restrict__ als, const float* __restrict__ ald, const void* __restrict__ b1,
    const int* __restrict__ rp, const int* __restrict__ psrc,
    u16* __restrict__ hrelu, int N, const int* __restrict__ flag){
  __shared__ int   sbuf[4][64];
  __shared__ float ebT[4][4*68];
  const bool isbf = *flag != 0;
  int wave = threadIdx.x >> 6, lane = threadIdx.x & 63;
  int node = blockIdx.x*4 + wave;
  bool live = node < N;
  int nd = live ? node : 0;
  int hd = lane >> 4;
  int beg = __builtin_amdgcn_readfirstlane(rp[nd]);
  int end = __builtin_amdgcn_readfirstlane(rp[nd+1]);
  if (!live){ beg = 0; end = 0; }
  f32x4 adv = *(const f32x4*)(ald + nd*4);
  const char* hb = (const char*)h1;
  int lane4 = lane << 2;
  int* sb = sbuf[wave];
  float* eb = ebT[wave];
  float a0 = 0.f, a1 = 0.f;
  float sp0 = 0.f, sp1 = 0.f, sp2 = 0.f, sp3 = 0.f;
  for (int cbeg = beg; cbeg < end; cbeg += 64){
    int cnt = min(64, end - cbeg);
    int cnt4 = (cnt + 3) & ~3;
    int e = cbeg + lane;
    if (e < end){
      int s = psrc[e];
      f32x4 av = *(const f32x4*)(als + s*4);
      float l0 = av[0]+adv[0], l1 = av[1]+adv[1], l2 = av[2]+adv[2], l3 = av[3]+adv[3];
      l0 = fmaxf(l0, 0.2f*l0); l1 = fmaxf(l1, 0.2f*l1);
      l2 = fmaxf(l2, 0.2f*l2); l3 = fmaxf(l3, 0.2f*l3);
      float e0 = __expf(l0), e1 = __expf(l1), e2 = __expf(l2), e3 = __expf(l3);
      sp0 += e0; sp1 += e1; sp2 += e2; sp3 += e3;
      sb[lane] = s << 8;                       // row byte offset (256 B rows)
      eb[0*68 + lane] = e0; eb[1*68 + lane] = e1;
      eb[2*68 + lane] = e2; eb[3*68 + lane] = e3;
    } else if (lane < cnt4){
      sb[lane] = 0;
      eb[0*68 + lane] = 0.f; eb[1*68 + lane] = 0.f;
      eb[2*68 + lane] = 0.f; eb[3*68 + lane] = 0.f;
    }
    for (int j0 = 0; j0 < cnt; j0 += 4){
      i32x4 off4 = *(const i32x4*)&sb[j0];                 // uniform b128 broadcast
      f32x4 ex4  = *(const f32x4*)&eb[hd*68 + j0];         // per-head-group b128
      u32 p[4];
      #pragma unroll
      for (int i=0;i<4;i++) p[i] = *(const u32*)(hb + (u32)(off4[i] + lane4));
      #pragma unroll
      for (int i=0;i<4;i++){
        union{u32 u; float f;} w;
        w.u = p[i] << 16;         a0 += ex4[i]*w.f;
        w.u = p[i] & 0xffff0000u; a1 += ex4[i]*w.f;
      }
    }
  }
  float s0 = wred(sp0), s1 = wred(sp1), s2 = wred(sp2), s3 = wred(sp3);
  float sum = hd == 0 ? s0 : hd == 1 ? s1 : hd == 2 ? s2 : s3;
  if (live){
    float inv = 1.f/(sum + 1e-16f);
    float v0 = a0*inv + loadv(b1, 2*lane,     isbf);
    float v1 = a1*inv + loadv(b1, 2*lane + 1, isbf);
    v0 = v0 > 0.f ? v0 : 0.f;
    v1 = v1 > 0.f ? v1 : 0.f;
    u32 packed = (u32)f2b(v0) | ((u32)f2b(v1) << 16);
    *(u32*)(hrelu + (size_t)node*128 + 2*lane) = packed;
  }
}

// ---------------- layer-2 aggregation + head-mean + bias + log_softmax ----------------
__global__ __launch_bounds__(256) void agg2(const u16* __restrict__ h2,
    const float* __restrict__ als, const float* __restrict__ ald, const void* __restrict__ b2,
    const int* __restrict__ rp, const int* __restrict__ psrc,
    void* __restrict__ out, int N, const int* __restrict__ flag){
  __shared__ int   sbuf[4][64];
  __shared__ float ebT[4][4*68];
  __shared__ float sm[4][160];
  const bool isbf = *flag != 0;
  int wave = threadIdx.x >> 6, lane = threadIdx.x & 63;
  int node = blockIdx.x*4 + wave;
  bool live = node < N;
  int nd = live ? node : 0;
  int hA = lane / 20;                 // pairA: lane -> channels 2l,2l+1 ; head = pair/20
  bool hasB = lane < 16;              // pairB: 64+lane -> channels 128+2l (head 3)
  int beg = __builtin_amdgcn_readfirstlane(rp[nd]);
  int end = __builtin_amdgcn_readfirstlane(rp[nd+1]);
  if (!live){ beg = 0; end = 0; }
  f32x4 adv = *(const f32x4*)(ald + nd*4);
  const char* hb = (const char*)h2;
  int lane4 = lane << 2;
  int* sb = sbuf[wave];
  float* eb = ebT[wave];
  float aA0 = 0.f, aA1 = 0.f, aB0 = 0.f, aB1 = 0.f;
  float sp0 = 0.f, sp1 = 0.f, sp2 = 0.f, sp3 = 0.f;
  for (int cbeg = beg; cbeg < end; cbeg += 64){
    int cnt = min(64, end - cbeg);
    int cnt4 = (cnt + 3) & ~3;
    int e = cbeg + lane;
    if (e < end){
      int s = psrc[e];
      f32x4 av = *(const f32x4*)(als + s*4);
      float l0 = av[0]+adv[0], l1 = av[1]+adv[1], l2 = av[2]+adv[2], l3 = av[3]+adv[3];
      l0 = fmaxf(l0, 0.2f*l0); l1 = fmaxf(l1, 0.2f*l1);
      l2 = fmaxf(l2, 0.2f*l2); l3 = fmaxf(l3, 0.2f*l3);
      float e0 = __expf(l0), e1 = __expf(l1), e2 = __expf(l2), e3 = __expf(l3);
      sp0 += e0; sp1 += e1; sp2 += e2; sp3 += e3;
      sb[lane] = s * 320;                      // row byte offset (320 B rows)
      eb[0*68 + lane] = e0; eb[1*68 + lane] = e1;
      eb[2*68 + lane] = e2; eb[3*68 + lane] = e3;
    } else if (lane < cnt4){
      sb[lane] = 0;
      eb[0*68 + lane] = 0.f; eb[1*68 + lane] = 0.f;
      eb[2*68 + lane] = 0.f; eb[3*68 + lane] = 0.f;
    }
    for (int j0 = 0; j0 < cnt; j0 += 4){
      i32x4 off4 = *(const i32x4*)&sb[j0];                 // uniform b128
      f32x4 exA4 = *(const f32x4*)&eb[hA*68 + j0];         // per-head-group b128
      f32x4 exB4 = *(const f32x4*)&eb[3*68 + j0];          // uniform b128
      u32 p[4], q[4];
      #pragma unroll
      for (int i=0;i<4;i++){
        u32 vo = (u32)(off4[i] + lane4);
        p[i] = *(const u32*)(hb + vo);
        if (hasB) q[i] = *(const u32*)(hb + vo + 256);
      }
      #pragma unroll
      for (int i=0;i<4;i++){
        union{u32 u; float f;} w;
        w.u = p[i] << 16;         aA0 += exA4[i]*w.f;
        w.u = p[i] & 0xffff0000u; aA1 += exA4[i]*w.f;
        if (hasB){
          w.u = q[i] << 16;         aB0 += exB4[i]*w.f;
          w.u = q[i] & 0xffff0000u; aB1 += exB4[i]*w.f;
        }
      }
    }
  }
  float s0 = wred(sp0), s1 = wred(sp1), s2 = wred(sp2), s3 = wred(sp3);
  float sumA = hA == 0 ? s0 : hA == 1 ? s1 : hA == 2 ? s2 : s3;
  float invA = 1.f/(sumA + 1e-16f);
  sm[wave][2*lane]     = aA0*invA;
  sm[wave][2*lane + 1] = aA1*invA;
  if (hasB){
    float invB = 1.f/(s3 + 1e-16f);
    sm[wave][128 + 2*lane] = aB0*invB;
    sm[wave][129 + 2*lane] = aB1*invB;
  }
  __syncthreads();
  float v = -__builtin_inff();
  if (lane < 40)
    v = (sm[wave][lane] + sm[wave][40+lane] + sm[wave][80+lane] + sm[wave][120+lane]) * 0.25f
        + loadv(b2, lane, isbf);
  float mxo = v;
  for (int o = 32; o; o >>= 1) mxo = fmaxf(mxo, __shfl_xor(mxo, o));
  float ex = (lane < 40) ? __expf(v - mxo) : 0.f;
  float S = ex;
  for (int o = 32; o; o >>= 1) S += __shfl_xor(S, o);
  if (live && lane < 40){
    float r = v - mxo - __logf(S);
    if (isbf) ((u16*)out)[(size_t)node*40 + lane] = f2b(r);
    else      ((float*)out)[(size_t)node*40 + lane] = r;
  }
}

extern "C" void kernel_launch(void* const* d_in, const int* in_sizes, int n_in,
                              void* d_out, int out_size, void* d_ws, size_t ws_size,
                              hipStream_t stream){
  const void* x   = d_in[0];
  const int*  ei  = (const int*)d_in[1];
  const void* W1  = d_in[2];
  const void* as1 = d_in[3];
  const void* ad1 = d_in[4];
  const void* b1  = d_in[5];
  const void* W2  = d_in[6];
  const void* as2 = d_in[7];
  const void* ad2 = d_in[8];
  const void* b2  = d_in[9];

  const int N = in_sizes[0] / 128;
  const int E = in_sizes[1] / 2;
  const int* esrc = ei;
  const int* edst = ei + E;

  char* w = (char*)d_ws;
  size_t off = 0;
  auto take = [&](size_t bytes)->void*{
    void* p = w + off;
    off = (off + bytes + 255) & ~(size_t)255;
    return p;
  };
  u16*   h12    = (u16*)take((size_t)N*160*2);   // h1 [N,128] then h2 [N,160] (aliased)
  u16*   hrelu  = (u16*)take((size_t)N*128*2);
  float* als1   = (float*)take((size_t)N*4*4);
  float* ald1   = (float*)take((size_t)N*4*4);
  float* als2   = (float*)take((size_t)N*4*4);
  float* ald2   = (float*)take((size_t)N*4*4);
  int*   rowptr = (int*)take((size_t)(N+1)*4);
  int*   counts = (int*)take((size_t)N*4);
  int*   bsum   = (int*)take(1024*4);
  int*   bscan  = (int*)take(1024*4);
  int*   psrc   = (int*)take((size_t)E*4);
  int*   flag   = (int*)take(64);

  const int B = (N + 255) / 256;
  const int NCHUNK = 128;               // blocks per region-group; grid = 8*NCHUNK

  detect_bf16<<<1, 256, 0, stream>>>(x, N*128, flag);

  // CSR by dst (XCD-partitioned count & scatter)
  hipMemsetAsync(counts, 0, (size_t)N*4, stream);
  count_x<<<8*NCHUNK, 256, 0, stream>>>(edst, counts, E, N, NCHUNK);
  scan_bsum<<<B, 256, 0, stream>>>(counts, bsum, N);
  scan_top<<<1, 1024, 0, stream>>>(bsum, bscan, B);
  scan_final<<<B, 256, 0, stream>>>(counts, bscan, rowptr, N, E);
  hipMemsetAsync(counts, 0, (size_t)N*4, stream);
  scatter_x<<<8*NCHUNK, 256, 0, stream>>>(esrc, edst, rowptr, counts, psrc, E, N, NCHUNK);

  // layer 1
  gemm_k<128><<<(N+63)/64, 256, 0, stream>>>(x, W1, h12, N, flag, flag);
  al_k<32><<<(4*N+255)/256, 256, 0, stream>>>(h12, as1, ad1, als1, ald1, N, flag);
  agg1<<<(N+3)/4, 256, 0, stream>>>(h12, als1, ald1, b1, rowptr, psrc, hrelu, N, flag);

  // layer 2 (h2 overwrites h1 region; hrelu input is internal bf16 -> flag+1)
  gemm_k<160><<<(N+63)/64, 256, 0, stream>>>(hrelu, W2, h12, N, flag+1, flag);
  al_k<40><<<(4*N+255)/256, 256, 0, stream>>>(h12, as2, ad2, als2, ald2, N, flag);
  agg2<<<(N+3)/4, 256, 0, stream>>>(h12, als2, ald2, b2, rowptr, psrc, d_out, N, flag);
}